// Round 7
// baseline (382.354 us; speedup 1.0000x reference)
//
#include <hip/hip_runtime.h>
#include <math.h>

#define NN 30000
#define EE 480000
#define BB 64

typedef __bf16 b16x8 __attribute__((ext_vector_type(8)));
typedef float  f32x4 __attribute__((ext_vector_type(4)));
typedef unsigned short u16x8 __attribute__((ext_vector_type(8)));

// ---------------- helpers ----------------
__device__ __forceinline__ float wsum64(float v){
  #pragma unroll
  for (int m = 32; m >= 1; m >>= 1) v += __shfl_xor(v, m, 64);
  return v;
}
__device__ __forceinline__ float wmax64(float v){
  #pragma unroll
  for (int m = 32; m >= 1; m >>= 1) v = fmaxf(v, __shfl_xor(v, m, 64));
  return v;
}
__device__ __forceinline__ float wsum16(float v){
  #pragma unroll
  for (int m = 1; m < 16; m <<= 1) v += __shfl_xor(v, m, 64);
  return v;
}
__device__ __forceinline__ unsigned short f2b(float f){   // fp32 -> bf16 RNE
  union { float f; unsigned u; } v; v.f = f;
  unsigned r = v.u + 0x7fffu + ((v.u >> 16) & 1u);
  return (unsigned short)(r >> 16);
}
__device__ __forceinline__ float b2f(unsigned short u){
  union { unsigned u; float f; } v; v.u = ((unsigned)u) << 16;
  return v.f;
}

// ---------------- CSR build ----------------
__global__ void hist_kernel(const int* __restrict__ dst, int* __restrict__ deg){
  int e = blockIdx.x*256 + threadIdx.x;
  if (e < EE) atomicAdd(&deg[dst[e]], 1);
}

// one-pass multi-block scan: block b redundantly sums deg[0..b*256) then LDS-scans its 256.
__global__ __launch_bounds__(256) void scan_kernel(const int* __restrict__ deg, int* __restrict__ rowptr){
  __shared__ int s[256];
  __shared__ int wred[4];
  const int b = blockIdx.x, tid = threadIdx.x;
  const int base = b*256;
  int part = 0;
  for (int idx = tid; idx < base; idx += 256) part += deg[idx];
  #pragma unroll
  for (int m = 32; m >= 1; m >>= 1) part += __shfl_xor(part, m, 64);
  if ((tid & 63) == 0) wred[tid >> 6] = part;
  __syncthreads();
  int offset = wred[0] + wred[1] + wred[2] + wred[3];
  int n = base + tid;
  int d = (n < NN) ? deg[n] : 0;
  s[tid] = d;
  __syncthreads();
  for (int off = 1; off < 256; off <<= 1){
    int v = (tid >= off) ? s[tid - off] : 0;
    __syncthreads();
    s[tid] += v;
    __syncthreads();
  }
  if (n < NN) rowptr[n] = offset + s[tid] - d;   // exclusive
  if (b == 0 && tid == 0) rowptr[NN] = EE;
}

// ---------------- prep: fully parallel W transposes (bf16) + wae dots ----------------
__global__ void prep_kernel(const float* __restrict__ W1, const float* __restrict__ W2,
                            const float* __restrict__ We1, const float* __restrict__ ae1,
                            const float* __restrict__ We2, const float* __restrict__ ae2,
                            unsigned short* __restrict__ W1t, unsigned short* __restrict__ W2t,
                            float* __restrict__ wae){
  int t = threadIdx.x, b = blockIdx.x;
  if (b < 128){
    W1t[t*128 + b] = f2b(W1[b*256 + t]);
  } else if (b < 384){
    int k = b - 128;
    if (t < 64) W2t[t*256 + k] = f2b(W2[k*64 + t]);
  } else {
    if (t < 128){
      int h = t >> 5, k = t & 31;
      float s = 0.f;
      for (int f = 0; f < 64; f++) s += We1[k*256 + h*64 + f] * ae1[h*64 + f];
      wae[h*32 + k] = s;
    } else if (t < 160){
      int k = t - 128;
      float s = 0.f;
      for (int f = 0; f < 64; f++) s += We2[k*64 + f] * ae2[f];
      wae[128 + k] = s;
    }
  }
}

// ---------------- streaming edge dots: 8 lanes/edge, NO atomics, e-ordered output ----------------
__global__ __launch_bounds__(256) void edot_kernel(const float* __restrict__ ea,
    const float* __restrict__ wae, float4* __restrict__ dlo, float2* __restrict__ dhi){
  __shared__ float s_w[160];
  if (threadIdx.x < 160) s_w[threadIdx.x] = wae[threadIdx.x];
  __syncthreads();
  const int lane = threadIdx.x & 63;
  const int il = lane & 7;
  const int e = blockIdx.x*32 + (threadIdx.x >> 3);
  if (e >= EE) return;
  float4 v = *(const float4*)(ea + (size_t)e*32 + il*4);   // 1KB per wave, coalesced
  float dots[5];
  #pragma unroll
  for (int h = 0; h < 5; h++){
    float4 w = *(const float4*)&s_w[h*32 + il*4];
    dots[h] = v.x*w.x + v.y*w.y + v.z*w.z + v.w*w.w;
  }
  #pragma unroll
  for (int m = 1; m < 8; m <<= 1)
    #pragma unroll
    for (int h = 0; h < 5; h++) dots[h] += __shfl_xor(dots[h], m, 64);
  if (il == 0){
    float4 lo; lo.x = dots[0]; lo.y = dots[1]; lo.z = dots[2]; lo.w = dots[3];
    dlo[e] = lo;
  } else if (il == 1){
    float2 hi; hi.x = dots[4]; hi.y = 0.f;
    dhi[e] = hi;
  }
}

// ---------------- scatter: thread per edge, full-wave atomic parallelism, 32B record ----------------
// rec[slot] (8 floats): [0..3]=edot1, [4]=edot2, [5]=src(int bits), [6,7]=pad
__global__ __launch_bounds__(256) void scatter_kernel(const float4* __restrict__ dlo,
    const float2* __restrict__ dhi, const int* __restrict__ src, const int* __restrict__ dst,
    const int* __restrict__ rowptr, int* __restrict__ cursor, float* __restrict__ rec){
  int e = blockIdx.x*256 + threadIdx.x;
  if (e >= EE) return;
  int dd = dst[e];
  int slot = rowptr[dd] + atomicAdd(&cursor[dd], 1);
  float4 lo = dlo[e];
  float2 hi = dhi[e];
  float4 hiv; hiv.x = hi.x; hiv.y = __int_as_float(src[e]); hiv.z = 0.f; hiv.w = 0.f;
  *(float4*)(rec + (size_t)slot*8) = lo;
  *(float4*)(rec + (size_t)slot*8 + 4) = hiv;
}

// ---------------- GEMM1: MFMA bf16, 128 rows, all 4 heads looped in-block ----------------
__global__ __launch_bounds__(256) void gemm1_mfma(const float* __restrict__ x,
    const unsigned short* __restrict__ Bt, const float* __restrict__ a_s, const float* __restrict__ a_d,
    unsigned short* __restrict__ out, float* __restrict__ alsrc, float* __restrict__ aldst){
  __shared__ unsigned short As[128*136];
  __shared__ unsigned short Bs[64*136];
  const int tid = threadIdx.x;
  const int w = tid >> 6, lane = tid & 63;
  const int c = lane & 15, gq = lane >> 4;
  const int m0 = blockIdx.x * 128;
  #pragma unroll
  for (int q = 0; q < 16; q++){
    int ch = tid*16 + q;
    int r = ch >> 5, off = (ch & 31)*4;
    int grow = m0 + r;
    ushort4 o;
    if (grow < NN){
      float4 v = *(const float4*)(x + (size_t)grow*128 + off);
      o.x = f2b(v.x); o.y = f2b(v.y); o.z = f2b(v.z); o.w = f2b(v.w);
    } else o = make_ushort4(0,0,0,0);
    *(ushort4*)&As[r*136 + off] = o;
  }
  #pragma unroll
  for (int q = 0; q < 4; q++){
    int ch = tid*4 + q;
    int n = ch >> 4, off = (ch & 15)*8;
    *(ulonglong2*)&Bs[n*136 + off] = *(const ulonglong2*)(Bt + (size_t)n*128 + off);
  }
  __syncthreads();
  for (int head = 0; head < 4; head++){
    f32x4 acc[2][4];
    #pragma unroll
    for (int mt = 0; mt < 2; mt++)
      #pragma unroll
      for (int nt = 0; nt < 4; nt++) acc[mt][nt] = (f32x4){0.f,0.f,0.f,0.f};
    #pragma unroll
    for (int k0 = 0; k0 < 128; k0 += 32){
      b16x8 afr[2], bfr[4];
      #pragma unroll
      for (int mt = 0; mt < 2; mt++)
        afr[mt] = *(const b16x8*)&As[(w*32 + mt*16 + c)*136 + k0 + gq*8];
      #pragma unroll
      for (int nt = 0; nt < 4; nt++)
        bfr[nt] = *(const b16x8*)&Bs[(nt*16 + c)*136 + k0 + gq*8];
      #pragma unroll
      for (int mt = 0; mt < 2; mt++)
        #pragma unroll
        for (int nt = 0; nt < 4; nt++)
          acc[mt][nt] = __builtin_amdgcn_mfma_f32_16x16x32_bf16(afr[mt], bfr[nt], acc[mt][nt], 0, 0, 0);
    }
    __syncthreads();
    if (head < 3){
      #pragma unroll
      for (int q = 0; q < 4; q++){
        int ch = tid*4 + q;
        int n = ch >> 4, off = (ch & 15)*8;
        *(ulonglong2*)&Bs[n*136 + off] = *(const ulonglong2*)(Bt + (size_t)((head+1)*64 + n)*128 + off);
      }
    }
    float asv[4], adv[4];
    #pragma unroll
    for (int nt = 0; nt < 4; nt++){
      asv[nt] = a_s[head*64 + nt*16 + c];
      adv[nt] = a_d[head*64 + nt*16 + c];
    }
    #pragma unroll
    for (int mt = 0; mt < 2; mt++){
      int base_row = m0 + w*32 + mt*16 + gq*4;
      #pragma unroll
      for (int r = 0; r < 4; r++){
        int row = base_row + r;
        float ps = 0.f, pd = 0.f;
        #pragma unroll
        for (int nt = 0; nt < 4; nt++){
          ps += acc[mt][nt][r] * asv[nt];
          pd += acc[mt][nt][r] * adv[nt];
        }
        ps = wsum16(ps); pd = wsum16(pd);
        if (row < NN){
          if (c == 0){
            alsrc[(size_t)row*4 + head] = ps;
            aldst[(size_t)row*4 + head] = pd;
          }
          #pragma unroll
          for (int nt = 0; nt < 4; nt++)
            out[(size_t)row*256 + head*64 + nt*16 + c] = f2b(acc[mt][nt][r]);
        }
      }
    }
    if (head < 3) __syncthreads();
  }
}

// ---------------- GEMM2: MFMA bf16, BN(from raw stats)+ReLU fused on A ----------------
__global__ __launch_bounds__(256) void gemm2_mfma(const unsigned short* __restrict__ Ab,
    const unsigned short* __restrict__ Bt,
    const float* __restrict__ cs, const float* __restrict__ csq,
    const float* __restrict__ g, const float* __restrict__ b,
    const float* __restrict__ a_s, const float* __restrict__ a_d,
    unsigned short* __restrict__ out, float* __restrict__ alsrc, float* __restrict__ aldst){
  __shared__ unsigned short As[128*136];
  __shared__ unsigned short Bs[64*136];
  __shared__ float s_scale[256], s_shift[256];
  const int tid = threadIdx.x;
  const int w = tid >> 6, lane = tid & 63;
  const int c = lane & 15, gq = lane >> 4;
  const int m0 = blockIdx.x * 128;
  if (tid < 256){
    float mu  = cs[tid]  * (1.f/NN);
    float var = csq[tid] * (1.f/NN) - mu*mu;
    float rs  = rsqrtf(var + 1e-5f);
    float sc  = rs * g[tid];
    s_scale[tid] = sc;
    s_shift[tid] = b[tid] - mu*sc;
  }
  __syncthreads();
  f32x4 acc[2][4];
  #pragma unroll
  for (int mt = 0; mt < 2; mt++)
    #pragma unroll
    for (int nt = 0; nt < 4; nt++) acc[mt][nt] = (f32x4){0.f,0.f,0.f,0.f};
  for (int kp = 0; kp < 256; kp += 128){
    #pragma unroll
    for (int q = 0; q < 16; q++){
      int ch = tid*16 + q;
      int r = ch >> 5, off = (ch & 31)*4;
      int grow = m0 + r;
      ushort4 o;
      if (grow < NN){
        ushort4 v = *(const ushort4*)(Ab + (size_t)grow*256 + kp + off);
        float4 sc = *(const float4*)&s_scale[kp + off];
        float4 sh = *(const float4*)&s_shift[kp + off];
        o.x = f2b(fmaxf(fmaf(b2f(v.x), sc.x, sh.x), 0.f));
        o.y = f2b(fmaxf(fmaf(b2f(v.y), sc.y, sh.y), 0.f));
        o.z = f2b(fmaxf(fmaf(b2f(v.z), sc.z, sh.z), 0.f));
        o.w = f2b(fmaxf(fmaf(b2f(v.w), sc.w, sh.w), 0.f));
      } else o = make_ushort4(0,0,0,0);
      *(ushort4*)&As[r*136 + off] = o;
    }
    #pragma unroll
    for (int q = 0; q < 4; q++){
      int ch = tid*4 + q;
      int n = ch >> 4, off = (ch & 15)*8;
      *(ulonglong2*)&Bs[n*136 + off] = *(const ulonglong2*)(Bt + (size_t)n*256 + kp + off);
    }
    __syncthreads();
    #pragma unroll
    for (int k0 = 0; k0 < 128; k0 += 32){
      b16x8 afr[2], bfr[4];
      #pragma unroll
      for (int mt = 0; mt < 2; mt++)
        afr[mt] = *(const b16x8*)&As[(w*32 + mt*16 + c)*136 + k0 + gq*8];
      #pragma unroll
      for (int nt = 0; nt < 4; nt++)
        bfr[nt] = *(const b16x8*)&Bs[(nt*16 + c)*136 + k0 + gq*8];
      #pragma unroll
      for (int mt = 0; mt < 2; mt++)
        #pragma unroll
        for (int nt = 0; nt < 4; nt++)
          acc[mt][nt] = __builtin_amdgcn_mfma_f32_16x16x32_bf16(afr[mt], bfr[nt], acc[mt][nt], 0, 0, 0);
    }
    __syncthreads();
  }
  float asv[4], adv[4];
  #pragma unroll
  for (int nt = 0; nt < 4; nt++){
    asv[nt] = a_s[nt*16 + c];
    adv[nt] = a_d[nt*16 + c];
  }
  #pragma unroll
  for (int mt = 0; mt < 2; mt++){
    int base_row = m0 + w*32 + mt*16 + gq*4;
    #pragma unroll
    for (int r = 0; r < 4; r++){
      int row = base_row + r;
      float ps = 0.f, pd = 0.f;
      #pragma unroll
      for (int nt = 0; nt < 4; nt++){
        ps += acc[mt][nt][r] * asv[nt];
        pd += acc[mt][nt][r] * adv[nt];
      }
      ps = wsum16(ps); pd = wsum16(pd);
      if (row < NN){
        if (c == 0){
          alsrc[row] = ps;
          aldst[row] = pd;
        }
        #pragma unroll
        for (int nt = 0; nt < 4; nt++)
          out[(size_t)row*64 + nt*16 + c] = f2b(acc[mt][nt][r]);
      }
    }
  }
}

// ---------------- segment softmax + wide bf16 gather (deep-unrolled), 32B-record edges ----------------
template<int H>
__global__ __launch_bounds__(256) void agg_kernel(const int* __restrict__ rowptr,
    const float* __restrict__ rec,
    const float* __restrict__ al_src, const float* __restrict__ al_dst,
    const unsigned short* __restrict__ xsb, const float* __restrict__ bias,
    unsigned short* __restrict__ outb, float* __restrict__ outf){
  constexpr int CH = 128;
  __shared__ float s_e_all[4][CH*H];
  __shared__ int   s_src_all[4][CH];
  const int wid  = threadIdx.x >> 6;
  const int lane = threadIdx.x & 63;
  const int i = blockIdx.x*4 + wid;
  float* s_e  = s_e_all[wid];
  int*   s_src = s_src_all[wid];
  const int r0 = rowptr[i];
  const int d  = rowptr[i+1] - r0;
  float ad[H], asi[H];
  #pragma unroll
  for (int h = 0; h < H; h++){ ad[h] = al_dst[(size_t)i*H+h]; asi[h] = al_src[(size_t)i*H+h]; }
  float sesum[H], m[H];
  #pragma unroll
  for (int h = 0; h < H; h++){ sesum[h] = 0.f; m[h] = -1e30f; }
  for (int t = lane; t < d; t += 64){
    const float* rp = rec + (size_t)(r0 + t)*8;
    float al[H];
    int sn;
    if constexpr (H == 4){
      float4 ev = *(const float4*)rp;
      float2 hi = *(const float2*)(rp + 4);
      sn = __float_as_int(hi.y);
      float4 av = *(const float4*)(al_src + (size_t)sn*4);
      al[0]=av.x+ad[0]+ev.x; al[1]=av.y+ad[1]+ev.y; al[2]=av.z+ad[2]+ev.z; al[3]=av.w+ad[3]+ev.w;
      sesum[0]+=ev.x; sesum[1]+=ev.y; sesum[2]+=ev.z; sesum[3]+=ev.w;
    } else {
      float2 hi = *(const float2*)(rp + 4);
      sn = __float_as_int(hi.y);
      al[0] = al_src[sn] + ad[0] + hi.x;
      sesum[0] += hi.x;
    }
    if (t < CH) s_src[t] = sn;
    #pragma unroll
    for (int h = 0; h < H; h++){
      float a = al[h]; a = a > 0.f ? a : 0.2f*a;
      if (t < CH) s_e[t*H+h] = a;
      m[h] = fmaxf(m[h], a);
    }
  }
  float invd = (d > 0) ? 1.f/(float)d : 0.f;
  float sa[H];
  #pragma unroll
  for (int h = 0; h < H; h++){
    sesum[h] = wsum64(sesum[h]);
    m[h] = wmax64(m[h]);
    float a = asi[h] + ad[h] + sesum[h]*invd;
    sa[h] = a > 0.f ? a : 0.2f*a;
    m[h] = fmaxf(m[h], sa[h]);
  }
  float acc8[8];
  #pragma unroll
  for (int j = 0; j < 8; j++) acc8[j] = 0.f;
  float dpart[H];
  #pragma unroll
  for (int h = 0; h < H; h++) dpart[h] = 0.f;
  const int half = lane >> 5, il5 = lane & 31;   // H==4 mapping
  const int grp  = lane >> 3, il3 = lane & 7;    // H==1 mapping
  int c0 = 0;
  while (c0 < d){
    int cl = min(CH, d - c0);
    if (c0 > 0){
      for (int t = lane; t < cl; t += 64){
        const float* rp = rec + (size_t)(r0 + c0 + t)*8;
        if constexpr (H == 4){
          float4 ev = *(const float4*)rp;
          float2 hi = *(const float2*)(rp + 4);
          int sn = __float_as_int(hi.y);
          s_src[t] = sn;
          float4 av = *(const float4*)(al_src + (size_t)sn*4);
          float a0=av.x+ad[0]+ev.x, a1=av.y+ad[1]+ev.y, a2=av.z+ad[2]+ev.z, a3=av.w+ad[3]+ev.w;
          s_e[t*4+0]=a0>0.f?a0:0.2f*a0; s_e[t*4+1]=a1>0.f?a1:0.2f*a1;
          s_e[t*4+2]=a2>0.f?a2:0.2f*a2; s_e[t*4+3]=a3>0.f?a3:0.2f*a3;
        } else {
          float2 hi = *(const float2*)(rp + 4);
          int sn = __float_as_int(hi.y);
          s_src[t] = sn;
          float a = al_src[sn] + ad[0] + hi.x;
          s_e[t] = a > 0.f ? a : 0.2f*a;
        }
      }
    }
    for (int t = lane; t < cl; t += 64){
      #pragma unroll
      for (int h = 0; h < H; h++){
        float e = __expf(s_e[t*H+h] - m[h]);
        s_e[t*H+h] = e;
        dpart[h] += e;
      }
    }
    __builtin_amdgcn_wave_barrier();
    if constexpr (H == 4){
      const int hd = il5 >> 3;
      int t = half;
      for (; t + 6 < cl; t += 8){             // 4 edges in flight per half-wave
        int sn0 = s_src[t],   sn1 = s_src[t+2], sn2 = s_src[t+4], sn3 = s_src[t+6];
        float w0 = s_e[t*4+hd],     w1 = s_e[(t+2)*4+hd];
        float w2 = s_e[(t+4)*4+hd], w3 = s_e[(t+6)*4+hd];
        u16x8 u0 = *(const u16x8*)(xsb + (size_t)sn0*256 + il5*8);
        u16x8 u1 = *(const u16x8*)(xsb + (size_t)sn1*256 + il5*8);
        u16x8 u2 = *(const u16x8*)(xsb + (size_t)sn2*256 + il5*8);
        u16x8 u3 = *(const u16x8*)(xsb + (size_t)sn3*256 + il5*8);
        #pragma unroll
        for (int j = 0; j < 8; j++){
          acc8[j] += w0*b2f(u0[j]); acc8[j] += w1*b2f(u1[j]);
          acc8[j] += w2*b2f(u2[j]); acc8[j] += w3*b2f(u3[j]);
        }
      }
      for (; t < cl; t += 2){
        int sn = s_src[t];
        float wv = s_e[t*4 + hd];
        u16x8 u = *(const u16x8*)(xsb + (size_t)sn*256 + il5*8);
        #pragma unroll
        for (int j = 0; j < 8; j++) acc8[j] += wv * b2f(u[j]);
      }
    } else {
      int t = grp;
      for (; t + 8 < cl; t += 16){            // 16 edges in flight per wave
        int sn0 = s_src[t], sn1 = s_src[t+8];
        float w0 = s_e[t], w1 = s_e[t+8];
        u16x8 u0 = *(const u16x8*)(xsb + (size_t)sn0*64 + il3*8);
        u16x8 u1 = *(const u16x8*)(xsb + (size_t)sn1*64 + il3*8);
        #pragma unroll
        for (int j = 0; j < 8; j++){
          acc8[j] += w0*b2f(u0[j]); acc8[j] += w1*b2f(u1[j]);
        }
      }
      for (; t < cl; t += 8){
        int sn = s_src[t];
        float wv = s_e[t];
        u16x8 u = *(const u16x8*)(xsb + (size_t)sn*64 + il3*8);
        #pragma unroll
        for (int j = 0; j < 8; j++) acc8[j] += wv * b2f(u[j]);
      }
    }
    __builtin_amdgcn_wave_barrier();
    c0 += CH;
  }
  float es[H];
  #pragma unroll
  for (int h = 0; h < H; h++) es[h] = __expf(sa[h] - m[h]);
  if (lane == 0){
    #pragma unroll
    for (int h = 0; h < H; h++) dpart[h] += es[h];
  }
  if constexpr (H == 4){
    if (half == 0){
      float wv = es[il5 >> 3];
      u16x8 u = *(const u16x8*)(xsb + (size_t)i*256 + il5*8);
      #pragma unroll
      for (int j = 0; j < 8; j++) acc8[j] += wv * b2f(u[j]);
    }
  } else {
    if (grp == 0){
      float wv = es[0];
      u16x8 u = *(const u16x8*)(xsb + (size_t)i*64 + il3*8);
      #pragma unroll
      for (int j = 0; j < 8; j++) acc8[j] += wv * b2f(u[j]);
    }
  }
  float denom[H];
  #pragma unroll
  for (int h = 0; h < H; h++) denom[h] = wsum64(dpart[h]);
  if constexpr (H == 4){
    #pragma unroll
    for (int j = 0; j < 8; j++) acc8[j] += __shfl_xor(acc8[j], 32, 64);
    if (lane < 32){
      float inv = 1.f / denom[il5 >> 3];
      u16x8 o;
      #pragma unroll
      for (int j = 0; j < 8; j++) o[j] = f2b(acc8[j]*inv + bias[il5*8 + j]);
      *(u16x8*)(outb + (size_t)i*256 + il5*8) = o;
    }
  } else {
    #pragma unroll
    for (int j = 0; j < 8; j++){
      acc8[j] += __shfl_xor(acc8[j], 8, 64);
      acc8[j] += __shfl_xor(acc8[j], 16, 64);
      acc8[j] += __shfl_xor(acc8[j], 32, 64);
    }
    if (lane < 8){
      float inv = 1.f / denom[0];
      float4 o0, o1;
      o0.x = acc8[0]*inv + bias[il3*8+0]; o0.y = acc8[1]*inv + bias[il3*8+1];
      o0.z = acc8[2]*inv + bias[il3*8+2]; o0.w = acc8[3]*inv + bias[il3*8+3];
      o1.x = acc8[4]*inv + bias[il3*8+4]; o1.y = acc8[5]*inv + bias[il3*8+5];
      o1.z = acc8[6]*inv + bias[il3*8+6]; o1.w = acc8[7]*inv + bias[il3*8+7];
      *(float4*)(outf + (size_t)i*64 + il3*8)     = o0;
      *(float4*)(outf + (size_t)i*64 + il3*8 + 4) = o1;
    }
  }
}

// ---------------- BN stats ----------------
__global__ __launch_bounds__(256) void bn_stats_b16_kernel(const unsigned short* __restrict__ h,
    float* __restrict__ cs, float* __restrict__ csq){
  __shared__ float s_red[4][256], q_red[4][256];
  const int tid = threadIdx.x;
  const int wv = tid >> 6, lane = tid & 63;
  const int rg = lane >> 5, cg = lane & 31;
  float s8[8], q8[8];
  #pragma unroll
  for (int j = 0; j < 8; j++){ s8[j] = 0.f; q8[j] = 0.f; }
  for (int chunk = blockIdx.x; chunk < 3750; chunk += 256){
    int r = chunk*8 + wv*2 + rg;
    u16x8 u = *(const u16x8*)(h + (size_t)r*256 + cg*8);
    #pragma unroll
    for (int j = 0; j < 8; j++){
      float v = b2f(u[j]);
      s8[j] += v; q8[j] += v*v;
    }
  }
  #pragma unroll
  for (int j = 0; j < 8; j++){
    s8[j] += __shfl_xor(s8[j], 32, 64);
    q8[j] += __shfl_xor(q8[j], 32, 64);
  }
  if (lane < 32){
    #pragma unroll
    for (int j = 0; j < 8; j++){
      s_red[wv][cg*8 + j] = s8[j];
      q_red[wv][cg*8 + j] = q8[j];
    }
  }
  __syncthreads();
  if (tid < 256){
    float ts = s_red[0][tid] + s_red[1][tid] + s_red[2][tid] + s_red[3][tid];
    float tq = q_red[0][tid] + q_red[1][tid] + q_red[2][tid] + q_red[3][tid];
    atomicAdd(&cs[tid], ts);
    atomicAdd(&csq[tid], tq);
  }
}

__global__ __launch_bounds__(256) void bn_stats_f32_kernel(const float* __restrict__ h,
    float* __restrict__ cs, float* __restrict__ csq){
  int col = threadIdx.x & 63;
  int ro  = threadIdx.x >> 6;
  float s = 0.f, s2 = 0.f;
  for (int r = blockIdx.x*4 + ro; r < NN; r += 1024){
    float v = h[(size_t)r*64 + col];
    s += v; s2 += v*v;
  }
  atomicAdd(&cs[col], s);
  atomicAdd(&csq[col], s2);
}

// ---------------- pooling ----------------
__global__ __launch_bounds__(256) void gate_kernel(const float* __restrict__ h,
    const float* __restrict__ cs, const float* __restrict__ csq,
    const float* __restrict__ g2, const float* __restrict__ b2,
    const float* __restrict__ Wg, const float* __restrict__ bg,
    float* __restrict__ hn, float* __restrict__ gate){
  int wid = threadIdx.x >> 6, lane = threadIdx.x & 63;
  int n = blockIdx.x*4 + wid;
  float mu  = cs[lane]  * (1.f/NN);
  float var = csq[lane] * (1.f/NN) - mu*mu;
  float rs  = rsqrtf(var + 1e-5f);
  float sc  = rs * g2[lane];
  float sh  = b2[lane] - mu*sc;
  float v = h[(size_t)n*64 + lane];
  float xx = fmaxf(fmaf(v, sc, sh), 0.f);
  hn[(size_t)n*64 + lane] = xx;
  float p = wsum64(xx * Wg[lane]);
  if (lane == 0) gate[n] = p + bg[0];
}

__global__ __launch_bounds__(256) void pool_kernel(const int* __restrict__ batch,
    const float* __restrict__ gate, const float* __restrict__ hn, float* __restrict__ out){
  __shared__ float red[256];
  __shared__ float a_red[4][64], w_red[4];
  __shared__ int seb[2];
  int b = blockIdx.x, tid = threadIdx.x;
  int wv = tid >> 6, lane = tid & 63;
  if (tid < 2){
    int target = b + tid;
    int lo = 0, hi = NN;
    while (lo < hi){ int mid = (lo+hi) >> 1; if (batch[mid] < target) lo = mid+1; else hi = mid; }
    seb[tid] = lo;
  }
  __syncthreads();
  int s = seb[0], e = seb[1];
  if (e <= s){ if (tid < 64) out[b*64 + tid] = 0.f; return; }
  float mloc = -1e30f;
  for (int n = s + tid; n < e; n += 256) mloc = fmaxf(mloc, gate[n]);
  mloc = wmax64(mloc);
  if (lane == 0) red[wv] = mloc;
  __syncthreads();
  float m = fmaxf(fmaxf(red[0], red[1]), fmaxf(red[2], red[3]));
  int rgrp = tid >> 4, cq = tid & 15;
  f32x4 acc = (f32x4){0.f,0.f,0.f,0.f};
  float wp = 0.f;
  for (int n = s + rgrp; n < e; n += 16){
    float wgt = __expf(gate[n] - m);
    float4 v = *(const float4*)(hn + (size_t)n*64 + cq*4);
    acc[0] += wgt*v.x; acc[1] += wgt*v.y; acc[2] += wgt*v.z; acc[3] += wgt*v.w;
    if (cq == 0) wp += wgt;
  }
  #pragma unroll
  for (int j = 0; j < 4; j++){
    acc[j] += __shfl_xor(acc[j], 16, 64);
    acc[j] += __shfl_xor(acc[j], 32, 64);
  }
  wp += __shfl_xor(wp, 16, 64);
  wp += __shfl_xor(wp, 32, 64);
  if (lane < 16){
    #pragma unroll
    for (int j = 0; j < 4; j++) a_red[wv][lane*4 + j] = acc[j];
  }
  if (lane == 0) w_red[wv] = wp;
  __syncthreads();
  if (tid < 64){
    float tot = a_red[0][tid] + a_red[1][tid] + a_red[2][tid] + a_red[3][tid];
    float wsm = w_red[0] + w_red[1] + w_red[2] + w_red[3];
    out[b*64 + tid] = tot / wsm;
  }
}

// ---------------- host ----------------
extern "C" void kernel_launch(void* const* d_in, const int* in_sizes, int n_in,
                              void* d_out, int out_size, void* d_ws, size_t ws_size,
                              hipStream_t stream){
  const float* x     = (const float*)d_in[0];
  const float* ea    = (const float*)d_in[1];
  const int*   ei    = (const int*)d_in[2];
  const int*   batch = (const int*)d_in[3];
  const float* W1    = (const float*)d_in[4];
  const float* We1   = (const float*)d_in[5];
  const float* as1   = (const float*)d_in[6];
  const float* ad1   = (const float*)d_in[7];
  const float* ae1   = (const float*)d_in[8];
  const float* bias1 = (const float*)d_in[9];
  const float* g1    = (const float*)d_in[10];
  const float* b1    = (const float*)d_in[11];
  const float* W2    = (const float*)d_in[12];
  const float* We2   = (const float*)d_in[13];
  const float* as2   = (const float*)d_in[14];
  const float* ad2   = (const float*)d_in[15];
  const float* ae2   = (const float*)d_in[16];
  const float* bias2 = (const float*)d_in[17];
  const float* g2    = (const float*)d_in[18];
  const float* b2    = (const float*)d_in[19];
  const float* Wg    = (const float*)d_in[20];
  const float* bg    = (const float*)d_in[21];
  const int* srcI = ei;
  const int* dstI = ei + EE;

  char* ws = (char*)d_ws;
  int*   deg    = (int*)(ws + 0);
  int*   cursor = (int*)(ws + 120064);
  float* stats  = (float*)(ws + 240128);   // cs1@0 csq1@256 cs2@512 csq2@576
  int*   rowptr = (int*)(ws + 244224);
  float* wae    = (float*)(ws + 364288);
  unsigned short* W1t = (unsigned short*)(ws + 365056);
  unsigned short* W2t = (unsigned short*)(ws + 430592);
  float* alsrc  = (float*)(ws + 463360);
  float* aldst  = (float*)(ws + 943360);
  float* gateb  = (float*)(ws + 1423360);
  float* rec    = (float*)(ws + 1543424);   // E * 32B records
  unsigned short* xs1b = (unsigned short*)(ws + 16903424); // 30000*256 bf16
  unsigned short* h1b  = (unsigned short*)(ws + 32263424); // 30000*256 bf16
  unsigned short* xs2b = (unsigned short*)(ws + 47623424); // 30000*64 bf16
  float* h2     = (float*)(ws + 51463424);  // 30000*64 f32
  float* hn     = (float*)(ws + 59143424);  // 30000*64 f32
  float4* dlo   = (float4*)(ws + 66823424); // E*16B
  float2* dhi   = (float2*)(ws + 74503424); // E*8B
  // total ~78.3 MB

  (void)hipMemsetAsync(ws, 0, 244224, stream);   // deg, cursor, stats

  hist_kernel<<<1875, 256, 0, stream>>>(dstI, deg);
  scan_kernel<<<118, 256, 0, stream>>>(deg, rowptr);
  prep_kernel<<<385, 256, 0, stream>>>(W1, W2, We1, ae1, We2, ae2, W1t, W2t, wae);
  edot_kernel<<<15000, 256, 0, stream>>>(ea, wae, dlo, dhi);
  scatter_kernel<<<1875, 256, 0, stream>>>(dlo, dhi, srcI, dstI, rowptr, cursor, rec);

  // ---- layer 1 (H=4) ----
  gemm1_mfma<<<235, 256, 0, stream>>>(x, W1t, as1, ad1, xs1b, alsrc, aldst);
  agg_kernel<4><<<7500, 256, 0, stream>>>(rowptr, rec, alsrc, aldst, xs1b, bias1, h1b, nullptr);
  bn_stats_b16_kernel<<<256, 256, 0, stream>>>(h1b, stats + 0, stats + 256);

  // ---- layer 2 (H=1) ----
  gemm2_mfma<<<235, 256, 0, stream>>>(h1b, W2t, stats + 0, stats + 256, g1, b1,
                                      as2, ad2, xs2b, alsrc, aldst);
  agg_kernel<1><<<7500, 256, 0, stream>>>(rowptr, rec, alsrc, aldst, xs2b, bias2, nullptr, h2);
  bn_stats_f32_kernel<<<256, 256, 0, stream>>>(h2, stats + 512, stats + 576);

  // ---- pool ----
  gate_kernel<<<7500, 256, 0, stream>>>(h2, stats + 512, stats + 576, g2, b2, Wg, bg, hn, gateb);
  pool_kernel<<<64, 256, 0, stream>>>(batch, gateb, hn, (float*)d_out);
}

// Round 8
// 380.237 us; speedup vs baseline: 1.0056x; 1.0056x over previous
//
#include <hip/hip_runtime.h>
#include <math.h>

#define NN 30000
#define EE 480000
#define BB 64

typedef __bf16 b16x8 __attribute__((ext_vector_type(8)));
typedef float  f32x4 __attribute__((ext_vector_type(4)));
typedef unsigned short u16x8 __attribute__((ext_vector_type(8)));

// ---------------- helpers ----------------
__device__ __forceinline__ float wsum64(float v){
  #pragma unroll
  for (int m = 32; m >= 1; m >>= 1) v += __shfl_xor(v, m, 64);
  return v;
}
__device__ __forceinline__ float wmax64(float v){
  #pragma unroll
  for (int m = 32; m >= 1; m >>= 1) v = fmaxf(v, __shfl_xor(v, m, 64));
  return v;
}
__device__ __forceinline__ float wsum16(float v){
  #pragma unroll
  for (int m = 1; m < 16; m <<= 1) v += __shfl_xor(v, m, 64);
  return v;
}
__device__ __forceinline__ unsigned short f2b(float f){   // fp32 -> bf16 RNE
  union { float f; unsigned u; } v; v.f = f;
  unsigned r = v.u + 0x7fffu + ((v.u >> 16) & 1u);
  return (unsigned short)(r >> 16);
}
__device__ __forceinline__ float b2f(unsigned short u){
  union { unsigned u; float f; } v; v.u = ((unsigned)u) << 16;
  return v.f;
}

// ---------------- CSR build ----------------
__global__ void hist_kernel(const int* __restrict__ dst, int* __restrict__ deg){
  int e = blockIdx.x*256 + threadIdx.x;
  if (e < EE) atomicAdd(&deg[dst[e]], 1);
}

// one-pass multi-block scan: block b redundantly sums deg[0..b*256) then LDS-scans its 256.
__global__ __launch_bounds__(256) void scan_kernel(const int* __restrict__ deg, int* __restrict__ rowptr){
  __shared__ int s[256];
  __shared__ int wred[4];
  const int b = blockIdx.x, tid = threadIdx.x;
  const int base = b*256;
  int part = 0;
  for (int idx = tid; idx < base; idx += 256) part += deg[idx];
  #pragma unroll
  for (int m = 32; m >= 1; m >>= 1) part += __shfl_xor(part, m, 64);
  if ((tid & 63) == 0) wred[tid >> 6] = part;
  __syncthreads();
  int offset = wred[0] + wred[1] + wred[2] + wred[3];
  int n = base + tid;
  int d = (n < NN) ? deg[n] : 0;
  s[tid] = d;
  __syncthreads();
  for (int off = 1; off < 256; off <<= 1){
    int v = (tid >= off) ? s[tid - off] : 0;
    __syncthreads();
    s[tid] += v;
    __syncthreads();
  }
  if (n < NN) rowptr[n] = offset + s[tid] - d;   // exclusive
  if (b == 0 && tid == 0) rowptr[NN] = EE;
}

// ---------------- prep: fully parallel W transposes (bf16) + wae dots ----------------
__global__ void prep_kernel(const float* __restrict__ W1, const float* __restrict__ W2,
                            const float* __restrict__ We1, const float* __restrict__ ae1,
                            const float* __restrict__ We2, const float* __restrict__ ae2,
                            unsigned short* __restrict__ W1t, unsigned short* __restrict__ W2t,
                            float* __restrict__ wae){
  int t = threadIdx.x, b = blockIdx.x;
  if (b < 128){
    W1t[t*128 + b] = f2b(W1[b*256 + t]);
  } else if (b < 384){
    int k = b - 128;
    if (t < 64) W2t[t*256 + k] = f2b(W2[k*64 + t]);
  } else {
    if (t < 128){
      int h = t >> 5, k = t & 31;
      float s = 0.f;
      for (int f = 0; f < 64; f++) s += We1[k*256 + h*64 + f] * ae1[h*64 + f];
      wae[h*32 + k] = s;
    } else if (t < 160){
      int k = t - 128;
      float s = 0.f;
      for (int f = 0; f < 64; f++) s += We2[k*64 + f] * ae2[f];
      wae[128 + k] = s;
    }
  }
}

// ---------------- fused edge pass: thread/edge, scalar-uniform weights, 32B record ----------------
// rec[slot] (8 floats): [0..3]=edot1, [4]=edot2, [5]=src(int bits), [6,7]=pad
__global__ __launch_bounds__(256) void edge_kernel(const float* __restrict__ ea,
    const float* __restrict__ wae, const int* __restrict__ src, const int* __restrict__ dst,
    const int* __restrict__ rowptr, int* __restrict__ cursor, float* __restrict__ rec){
  int e = blockIdx.x*256 + threadIdx.x;
  if (e >= EE) return;
  int dd = dst[e];
  int slot = rowptr[dd] + atomicAdd(&cursor[dd], 1);   // issue early, overlaps loads
  int sv = src[e];
  const float4* row = (const float4*)(ea + (size_t)e*32);
  float dots[5] = {0.f, 0.f, 0.f, 0.f, 0.f};
  #pragma unroll
  for (int q = 0; q < 8; q++){
    float4 v = row[q];
    #pragma unroll
    for (int h = 0; h < 5; h++){
      float4 w = *(const float4*)(wae + h*32 + q*4);   // wave-uniform -> scalar loads
      dots[h] += v.x*w.x + v.y*w.y + v.z*w.z + v.w*w.w;
    }
  }
  float4 lo; lo.x = dots[0]; lo.y = dots[1]; lo.z = dots[2]; lo.w = dots[3];
  float4 hi; hi.x = dots[4]; hi.y = __int_as_float(sv); hi.z = 0.f; hi.w = 0.f;
  *(float4*)(rec + (size_t)slot*8) = lo;
  *(float4*)(rec + (size_t)slot*8 + 4) = hi;
}

// ---------------- GEMM1: MFMA bf16, 128x64 tile, grid (235, 4 heads) ----------------
__global__ __launch_bounds__(256) void gemm1_mfma(const float* __restrict__ x,
    const unsigned short* __restrict__ Bt, const float* __restrict__ a_s, const float* __restrict__ a_d,
    unsigned short* __restrict__ out, float* __restrict__ alsrc, float* __restrict__ aldst){
  __shared__ unsigned short As[128*136];
  __shared__ unsigned short Bs[64*136];
  const int tid = threadIdx.x;
  const int w = tid >> 6, lane = tid & 63;
  const int c = lane & 15, gq = lane >> 4;
  const int m0 = blockIdx.x * 128;
  const int head = blockIdx.y;
  #pragma unroll
  for (int q = 0; q < 16; q++){
    int ch = tid*16 + q;
    int r = ch >> 5, off = (ch & 31)*4;
    int grow = m0 + r;
    ushort4 o;
    if (grow < NN){
      float4 v = *(const float4*)(x + (size_t)grow*128 + off);
      o.x = f2b(v.x); o.y = f2b(v.y); o.z = f2b(v.z); o.w = f2b(v.w);
    } else o = make_ushort4(0,0,0,0);
    *(ushort4*)&As[r*136 + off] = o;
  }
  #pragma unroll
  for (int q = 0; q < 4; q++){
    int ch = tid*4 + q;
    int n = ch >> 4, off = (ch & 15)*8;
    *(ulonglong2*)&Bs[n*136 + off] = *(const ulonglong2*)(Bt + (size_t)(head*64 + n)*128 + off);
  }
  __syncthreads();
  f32x4 acc[2][4];
  #pragma unroll
  for (int mt = 0; mt < 2; mt++)
    #pragma unroll
    for (int nt = 0; nt < 4; nt++) acc[mt][nt] = (f32x4){0.f,0.f,0.f,0.f};
  #pragma unroll
  for (int k0 = 0; k0 < 128; k0 += 32){
    b16x8 afr[2], bfr[4];
    #pragma unroll
    for (int mt = 0; mt < 2; mt++)
      afr[mt] = *(const b16x8*)&As[(w*32 + mt*16 + c)*136 + k0 + gq*8];
    #pragma unroll
    for (int nt = 0; nt < 4; nt++)
      bfr[nt] = *(const b16x8*)&Bs[(nt*16 + c)*136 + k0 + gq*8];
    #pragma unroll
    for (int mt = 0; mt < 2; mt++)
      #pragma unroll
      for (int nt = 0; nt < 4; nt++)
        acc[mt][nt] = __builtin_amdgcn_mfma_f32_16x16x32_bf16(afr[mt], bfr[nt], acc[mt][nt], 0, 0, 0);
  }
  float asv[4], adv[4];
  #pragma unroll
  for (int nt = 0; nt < 4; nt++){
    asv[nt] = a_s[head*64 + nt*16 + c];
    adv[nt] = a_d[head*64 + nt*16 + c];
  }
  #pragma unroll
  for (int mt = 0; mt < 2; mt++){
    int base_row = m0 + w*32 + mt*16 + gq*4;
    #pragma unroll
    for (int r = 0; r < 4; r++){
      int row = base_row + r;
      float ps = 0.f, pd = 0.f;
      #pragma unroll
      for (int nt = 0; nt < 4; nt++){
        ps += acc[mt][nt][r] * asv[nt];
        pd += acc[mt][nt][r] * adv[nt];
      }
      ps = wsum16(ps); pd = wsum16(pd);
      if (row < NN){
        if (c == 0){
          alsrc[(size_t)row*4 + head] = ps;
          aldst[(size_t)row*4 + head] = pd;
        }
        #pragma unroll
        for (int nt = 0; nt < 4; nt++)
          out[(size_t)row*256 + head*64 + nt*16 + c] = f2b(acc[mt][nt][r]);
      }
    }
  }
}

// ---------------- GEMM2: MFMA bf16, 64x64 tile (470 blocks), BN+ReLU fused on A ----------------
__global__ __launch_bounds__(256) void gemm2_mfma(const unsigned short* __restrict__ Ab,
    const unsigned short* __restrict__ Bt,
    const float* __restrict__ cs, const float* __restrict__ csq,
    const float* __restrict__ g, const float* __restrict__ b,
    const float* __restrict__ a_s, const float* __restrict__ a_d,
    unsigned short* __restrict__ out, float* __restrict__ alsrc, float* __restrict__ aldst){
  __shared__ unsigned short As[64*136];
  __shared__ unsigned short Bs[64*136];
  __shared__ float s_scale[256], s_shift[256];
  const int tid = threadIdx.x;
  const int w = tid >> 6, lane = tid & 63;
  const int c = lane & 15, gq = lane >> 4;
  const int m0 = blockIdx.x * 64;
  {
    float mu  = cs[tid]  * (1.f/NN);
    float var = csq[tid] * (1.f/NN) - mu*mu;
    float rs  = rsqrtf(var + 1e-5f);
    float sc  = rs * g[tid];
    s_scale[tid] = sc;
    s_shift[tid] = b[tid] - mu*sc;
  }
  __syncthreads();
  f32x4 acc[4];
  #pragma unroll
  for (int nt = 0; nt < 4; nt++) acc[nt] = (f32x4){0.f,0.f,0.f,0.f};
  for (int kp = 0; kp < 256; kp += 128){
    #pragma unroll
    for (int q = 0; q < 8; q++){
      int ch = tid*8 + q;                  // 2048 chunks of 4
      int r = ch >> 5, off = (ch & 31)*4;
      int grow = m0 + r;
      ushort4 o;
      if (grow < NN){
        ushort4 v = *(const ushort4*)(Ab + (size_t)grow*256 + kp + off);
        float4 sc = *(const float4*)&s_scale[kp + off];
        float4 sh = *(const float4*)&s_shift[kp + off];
        o.x = f2b(fmaxf(fmaf(b2f(v.x), sc.x, sh.x), 0.f));
        o.y = f2b(fmaxf(fmaf(b2f(v.y), sc.y, sh.y), 0.f));
        o.z = f2b(fmaxf(fmaf(b2f(v.z), sc.z, sh.z), 0.f));
        o.w = f2b(fmaxf(fmaf(b2f(v.w), sc.w, sh.w), 0.f));
      } else o = make_ushort4(0,0,0,0);
      *(ushort4*)&As[r*136 + off] = o;
    }
    #pragma unroll
    for (int q = 0; q < 4; q++){
      int ch = tid*4 + q;
      int n = ch >> 4, off = (ch & 15)*8;
      *(ulonglong2*)&Bs[n*136 + off] = *(const ulonglong2*)(Bt + (size_t)n*256 + kp + off);
    }
    __syncthreads();
    #pragma unroll
    for (int k0 = 0; k0 < 128; k0 += 32){
      b16x8 afr = *(const b16x8*)&As[(w*16 + c)*136 + k0 + gq*8];
      b16x8 bfr[4];
      #pragma unroll
      for (int nt = 0; nt < 4; nt++)
        bfr[nt] = *(const b16x8*)&Bs[(nt*16 + c)*136 + k0 + gq*8];
      #pragma unroll
      for (int nt = 0; nt < 4; nt++)
        acc[nt] = __builtin_amdgcn_mfma_f32_16x16x32_bf16(afr, bfr[nt], acc[nt], 0, 0, 0);
    }
    __syncthreads();
  }
  float asv[4], adv[4];
  #pragma unroll
  for (int nt = 0; nt < 4; nt++){
    asv[nt] = a_s[nt*16 + c];
    adv[nt] = a_d[nt*16 + c];
  }
  int base_row = m0 + w*16 + gq*4;
  #pragma unroll
  for (int r = 0; r < 4; r++){
    int row = base_row + r;
    float ps = 0.f, pd = 0.f;
    #pragma unroll
    for (int nt = 0; nt < 4; nt++){
      ps += acc[nt][r] * asv[nt];
      pd += acc[nt][r] * adv[nt];
    }
    ps = wsum16(ps); pd = wsum16(pd);
    if (row < NN){
      if (c == 0){
        alsrc[row] = ps;
        aldst[row] = pd;
      }
      #pragma unroll
      for (int nt = 0; nt < 4; nt++)
        out[(size_t)row*64 + nt*16 + c] = f2b(acc[nt][r]);
    }
  }
}

// ---------------- segment softmax + wide bf16 gather (round-6 body), 32B-record edges ----------------
template<int H>
__global__ __launch_bounds__(256) void agg_kernel(const int* __restrict__ rowptr,
    const float* __restrict__ rec,
    const float* __restrict__ al_src, const float* __restrict__ al_dst,
    const unsigned short* __restrict__ xsb, const float* __restrict__ bias,
    unsigned short* __restrict__ outb, float* __restrict__ outf){
  constexpr int CH = 128;
  __shared__ float s_e_all[4][CH*H];
  __shared__ int   s_src_all[4][CH];
  const int wid  = threadIdx.x >> 6;
  const int lane = threadIdx.x & 63;
  const int i = blockIdx.x*4 + wid;
  float* s_e  = s_e_all[wid];
  int*   s_src = s_src_all[wid];
  const int r0 = rowptr[i];
  const int d  = rowptr[i+1] - r0;
  float ad[H], asi[H];
  #pragma unroll
  for (int h = 0; h < H; h++){ ad[h] = al_dst[(size_t)i*H+h]; asi[h] = al_src[(size_t)i*H+h]; }
  float sesum[H], m[H];
  #pragma unroll
  for (int h = 0; h < H; h++){ sesum[h] = 0.f; m[h] = -1e30f; }
  for (int t = lane; t < d; t += 64){
    const float* rp = rec + (size_t)(r0 + t)*8;
    float al[H];
    int sn;
    if constexpr (H == 4){
      float4 ev = *(const float4*)rp;
      float2 hi = *(const float2*)(rp + 4);
      sn = __float_as_int(hi.y);
      float4 av = *(const float4*)(al_src + (size_t)sn*4);
      al[0]=av.x+ad[0]+ev.x; al[1]=av.y+ad[1]+ev.y; al[2]=av.z+ad[2]+ev.z; al[3]=av.w+ad[3]+ev.w;
      sesum[0]+=ev.x; sesum[1]+=ev.y; sesum[2]+=ev.z; sesum[3]+=ev.w;
    } else {
      float2 hi = *(const float2*)(rp + 4);
      sn = __float_as_int(hi.y);
      al[0] = al_src[sn] + ad[0] + hi.x;
      sesum[0] += hi.x;
    }
    if (t < CH) s_src[t] = sn;
    #pragma unroll
    for (int h = 0; h < H; h++){
      float a = al[h]; a = a > 0.f ? a : 0.2f*a;
      if (t < CH) s_e[t*H+h] = a;
      m[h] = fmaxf(m[h], a);
    }
  }
  float invd = (d > 0) ? 1.f/(float)d : 0.f;
  float sa[H];
  #pragma unroll
  for (int h = 0; h < H; h++){
    sesum[h] = wsum64(sesum[h]);
    m[h] = wmax64(m[h]);
    float a = asi[h] + ad[h] + sesum[h]*invd;
    sa[h] = a > 0.f ? a : 0.2f*a;
    m[h] = fmaxf(m[h], sa[h]);
  }
  float acc8[8];
  #pragma unroll
  for (int j = 0; j < 8; j++) acc8[j] = 0.f;
  float dpart[H];
  #pragma unroll
  for (int h = 0; h < H; h++) dpart[h] = 0.f;
  const int half = lane >> 5, il5 = lane & 31;   // H==4 mapping
  const int grp  = lane >> 3, il3 = lane & 7;    // H==1 mapping
  int c0 = 0;
  while (c0 < d){
    int cl = min(CH, d - c0);
    if (c0 > 0){
      for (int t = lane; t < cl; t += 64){
        const float* rp = rec + (size_t)(r0 + c0 + t)*8;
        if constexpr (H == 4){
          float4 ev = *(const float4*)rp;
          float2 hi = *(const float2*)(rp + 4);
          int sn = __float_as_int(hi.y);
          s_src[t] = sn;
          float4 av = *(const float4*)(al_src + (size_t)sn*4);
          float a0=av.x+ad[0]+ev.x, a1=av.y+ad[1]+ev.y, a2=av.z+ad[2]+ev.z, a3=av.w+ad[3]+ev.w;
          s_e[t*4+0]=a0>0.f?a0:0.2f*a0; s_e[t*4+1]=a1>0.f?a1:0.2f*a1;
          s_e[t*4+2]=a2>0.f?a2:0.2f*a2; s_e[t*4+3]=a3>0.f?a3:0.2f*a3;
        } else {
          float2 hi = *(const float2*)(rp + 4);
          int sn = __float_as_int(hi.y);
          s_src[t] = sn;
          float a = al_src[sn] + ad[0] + hi.x;
          s_e[t] = a > 0.f ? a : 0.2f*a;
        }
      }
    }
    for (int t = lane; t < cl; t += 64){
      #pragma unroll
      for (int h = 0; h < H; h++){
        float e = __expf(s_e[t*H+h] - m[h]);
        s_e[t*H+h] = e;
        dpart[h] += e;
      }
    }
    __builtin_amdgcn_wave_barrier();
    if constexpr (H == 4){
      const int hd = il5 >> 3;
      for (int t = half; t < cl; t += 2){
        int sn = s_src[t];
        float wv = s_e[t*4 + hd];
        u16x8 u = *(const u16x8*)(xsb + (size_t)sn*256 + il5*8);
        #pragma unroll
        for (int j = 0; j < 8; j++) acc8[j] += wv * b2f(u[j]);
      }
    } else {
      for (int t = grp; t < cl; t += 8){
        int sn = s_src[t];
        float wv = s_e[t];
        u16x8 u = *(const u16x8*)(xsb + (size_t)sn*64 + il3*8);
        #pragma unroll
        for (int j = 0; j < 8; j++) acc8[j] += wv * b2f(u[j]);
      }
    }
    __builtin_amdgcn_wave_barrier();
    c0 += CH;
  }
  float es[H];
  #pragma unroll
  for (int h = 0; h < H; h++) es[h] = __expf(sa[h] - m[h]);
  if (lane == 0){
    #pragma unroll
    for (int h = 0; h < H; h++) dpart[h] += es[h];
  }
  if constexpr (H == 4){
    if (half == 0){
      float wv = es[il5 >> 3];
      u16x8 u = *(const u16x8*)(xsb + (size_t)i*256 + il5*8);
      #pragma unroll
      for (int j = 0; j < 8; j++) acc8[j] += wv * b2f(u[j]);
    }
  } else {
    if (grp == 0){
      float wv = es[0];
      u16x8 u = *(const u16x8*)(xsb + (size_t)i*64 + il3*8);
      #pragma unroll
      for (int j = 0; j < 8; j++) acc8[j] += wv * b2f(u[j]);
    }
  }
  float denom[H];
  #pragma unroll
  for (int h = 0; h < H; h++) denom[h] = wsum64(dpart[h]);
  if constexpr (H == 4){
    #pragma unroll
    for (int j = 0; j < 8; j++) acc8[j] += __shfl_xor(acc8[j], 32, 64);
    if (lane < 32){
      float inv = 1.f / denom[il5 >> 3];
      u16x8 o;
      #pragma unroll
      for (int j = 0; j < 8; j++) o[j] = f2b(acc8[j]*inv + bias[il5*8 + j]);
      *(u16x8*)(outb + (size_t)i*256 + il5*8) = o;
    }
  } else {
    #pragma unroll
    for (int j = 0; j < 8; j++){
      acc8[j] += __shfl_xor(acc8[j], 8, 64);
      acc8[j] += __shfl_xor(acc8[j], 16, 64);
      acc8[j] += __shfl_xor(acc8[j], 32, 64);
    }
    if (lane < 8){
      float inv = 1.f / denom[0];
      float4 o0, o1;
      o0.x = acc8[0]*inv + bias[il3*8+0]; o0.y = acc8[1]*inv + bias[il3*8+1];
      o0.z = acc8[2]*inv + bias[il3*8+2]; o0.w = acc8[3]*inv + bias[il3*8+3];
      o1.x = acc8[4]*inv + bias[il3*8+4]; o1.y = acc8[5]*inv + bias[il3*8+5];
      o1.z = acc8[6]*inv + bias[il3*8+6]; o1.w = acc8[7]*inv + bias[il3*8+7];
      *(float4*)(outf + (size_t)i*64 + il3*8)     = o0;
      *(float4*)(outf + (size_t)i*64 + il3*8 + 4) = o1;
    }
  }
}

// ---------------- BN stats ----------------
__global__ __launch_bounds__(256) void bn_stats_b16_kernel(const unsigned short* __restrict__ h,
    float* __restrict__ cs, float* __restrict__ csq){
  __shared__ float s_red[4][256], q_red[4][256];
  const int tid = threadIdx.x;
  const int wv = tid >> 6, lane = tid & 63;
  const int rg = lane >> 5, cg = lane & 31;
  float s8[8], q8[8];
  #pragma unroll
  for (int j = 0; j < 8; j++){ s8[j] = 0.f; q8[j] = 0.f; }
  for (int chunk = blockIdx.x; chunk < 3750; chunk += 256){
    int r = chunk*8 + wv*2 + rg;
    u16x8 u = *(const u16x8*)(h + (size_t)r*256 + cg*8);
    #pragma unroll
    for (int j = 0; j < 8; j++){
      float v = b2f(u[j]);
      s8[j] += v; q8[j] += v*v;
    }
  }
  #pragma unroll
  for (int j = 0; j < 8; j++){
    s8[j] += __shfl_xor(s8[j], 32, 64);
    q8[j] += __shfl_xor(q8[j], 32, 64);
  }
  if (lane < 32){
    #pragma unroll
    for (int j = 0; j < 8; j++){
      s_red[wv][cg*8 + j] = s8[j];
      q_red[wv][cg*8 + j] = q8[j];
    }
  }
  __syncthreads();
  if (tid < 256){
    float ts = s_red[0][tid] + s_red[1][tid] + s_red[2][tid] + s_red[3][tid];
    float tq = q_red[0][tid] + q_red[1][tid] + q_red[2][tid] + q_red[3][tid];
    atomicAdd(&cs[tid], ts);
    atomicAdd(&csq[tid], tq);
  }
}

__global__ __launch_bounds__(256) void bn_stats_f32_kernel(const float* __restrict__ h,
    float* __restrict__ cs, float* __restrict__ csq){
  int col = threadIdx.x & 63;
  int ro  = threadIdx.x >> 6;
  float s = 0.f, s2 = 0.f;
  for (int r = blockIdx.x*4 + ro; r < NN; r += 1024){
    float v = h[(size_t)r*64 + col];
    s += v; s2 += v*v;
  }
  atomicAdd(&cs[col], s);
  atomicAdd(&csq[col], s2);
}

// ---------------- pooling ----------------
__global__ __launch_bounds__(256) void gate_kernel(const float* __restrict__ h,
    const float* __restrict__ cs, const float* __restrict__ csq,
    const float* __restrict__ g2, const float* __restrict__ b2,
    const float* __restrict__ Wg, const float* __restrict__ bg,
    float* __restrict__ hn, float* __restrict__ gate){
  int wid = threadIdx.x >> 6, lane = threadIdx.x & 63;
  int n = blockIdx.x*4 + wid;
  float mu  = cs[lane]  * (1.f/NN);
  float var = csq[lane] * (1.f/NN) - mu*mu;
  float rs  = rsqrtf(var + 1e-5f);
  float sc  = rs * g2[lane];
  float sh  = b2[lane] - mu*sc;
  float v = h[(size_t)n*64 + lane];
  float xx = fmaxf(fmaf(v, sc, sh), 0.f);
  hn[(size_t)n*64 + lane] = xx;
  float p = wsum64(xx * Wg[lane]);
  if (lane == 0) gate[n] = p + bg[0];
}

__global__ __launch_bounds__(256) void pool_kernel(const int* __restrict__ batch,
    const float* __restrict__ gate, const float* __restrict__ hn, float* __restrict__ out){
  __shared__ float red[256];
  __shared__ float a_red[4][64], w_red[4];
  __shared__ int seb[2];
  int b = blockIdx.x, tid = threadIdx.x;
  int wv = tid >> 6, lane = tid & 63;
  if (tid < 2){
    int target = b + tid;
    int lo = 0, hi = NN;
    while (lo < hi){ int mid = (lo+hi) >> 1; if (batch[mid] < target) lo = mid+1; else hi = mid; }
    seb[tid] = lo;
  }
  __syncthreads();
  int s = seb[0], e = seb[1];
  if (e <= s){ if (tid < 64) out[b*64 + tid] = 0.f; return; }
  float mloc = -1e30f;
  for (int n = s + tid; n < e; n += 256) mloc = fmaxf(mloc, gate[n]);
  mloc = wmax64(mloc);
  if (lane == 0) red[wv] = mloc;
  __syncthreads();
  float m = fmaxf(fmaxf(red[0], red[1]), fmaxf(red[2], red[3]));
  int rgrp = tid >> 4, cq = tid & 15;
  f32x4 acc = (f32x4){0.f,0.f,0.f,0.f};
  float wp = 0.f;
  for (int n = s + rgrp; n < e; n += 16){
    float wgt = __expf(gate[n] - m);
    float4 v = *(const float4*)(hn + (size_t)n*64 + cq*4);
    acc[0] += wgt*v.x; acc[1] += wgt*v.y; acc[2] += wgt*v.z; acc[3] += wgt*v.w;
    if (cq == 0) wp += wgt;
  }
  #pragma unroll
  for (int j = 0; j < 4; j++){
    acc[j] += __shfl_xor(acc[j], 16, 64);
    acc[j] += __shfl_xor(acc[j], 32, 64);
  }
  wp += __shfl_xor(wp, 16, 64);
  wp += __shfl_xor(wp, 32, 64);
  if (lane < 16){
    #pragma unroll
    for (int j = 0; j < 4; j++) a_red[wv][lane*4 + j] = acc[j];
  }
  if (lane == 0) w_red[wv] = wp;
  __syncthreads();
  if (tid < 64){
    float tot = a_red[0][tid] + a_red[1][tid] + a_red[2][tid] + a_red[3][tid];
    float wsm = w_red[0] + w_red[1] + w_red[2] + w_red[3];
    out[b*64 + tid] = tot / wsm;
  }
}

// ---------------- host ----------------
extern "C" void kernel_launch(void* const* d_in, const int* in_sizes, int n_in,
                              void* d_out, int out_size, void* d_ws, size_t ws_size,
                              hipStream_t stream){
  const float* x     = (const float*)d_in[0];
  const float* ea    = (const float*)d_in[1];
  const int*   ei    = (const int*)d_in[2];
  const int*   batch = (const int*)d_in[3];
  const float* W1    = (const float*)d_in[4];
  const float* We1   = (const float*)d_in[5];
  const float* as1   = (const float*)d_in[6];
  const float* ad1   = (const float*)d_in[7];
  const float* ae1   = (const float*)d_in[8];
  const float* bias1 = (const float*)d_in[9];
  const float* g1    = (const float*)d_in[10];
  const float* b1    = (const float*)d_in[11];
  const float* W2    = (const float*)d_in[12];
  const float* We2   = (const float*)d_in[13];
  const float* as2   = (const float*)d_in[14];
  const float* ad2   = (const float*)d_in[15];
  const float* ae2   = (const float*)d_in[16];
  const float* bias2 = (const float*)d_in[17];
  const float* g2    = (const float*)d_in[18];
  const float* b2    = (const float*)d_in[19];
  const float* Wg    = (const float*)d_in[20];
  const float* bg    = (const float*)d_in[21];
  const int* srcI = ei;
  const int* dstI = ei + EE;

  char* ws = (char*)d_ws;
  int*   deg    = (int*)(ws + 0);
  int*   cursor = (int*)(ws + 120064);
  float* stats  = (float*)(ws + 240128);   // cs1@0 csq1@256 cs2@512 csq2@576
  int*   rowptr = (int*)(ws + 244224);
  float* wae    = (float*)(ws + 364288);
  unsigned short* W1t = (unsigned short*)(ws + 365056);
  unsigned short* W2t = (unsigned short*)(ws + 430592);
  float* alsrc  = (float*)(ws + 463360);
  float* aldst  = (float*)(ws + 943360);
  float* gateb  = (float*)(ws + 1423360);
  float* rec    = (float*)(ws + 1543424);   // E * 32B records
  unsigned short* xs1b = (unsigned short*)(ws + 16903424); // 30000*256 bf16
  unsigned short* h1b  = (unsigned short*)(ws + 32263424); // 30000*256 bf16
  unsigned short* xs2b = (unsigned short*)(ws + 47623424); // 30000*64 bf16
  float* h2     = (float*)(ws + 51463424);  // 30000*64 f32
  float* hn     = (float*)(ws + 59143424);  // 30000*64 f32
  // total ~66.8 MB

  (void)hipMemsetAsync(ws, 0, 244224, stream);   // deg, cursor, stats

  hist_kernel<<<1875, 256, 0, stream>>>(dstI, deg);
  scan_kernel<<<118, 256, 0, stream>>>(deg, rowptr);
  prep_kernel<<<385, 256, 0, stream>>>(W1, W2, We1, ae1, We2, ae2, W1t, W2t, wae);
  edge_kernel<<<1875, 256, 0, stream>>>(ea, wae, srcI, dstI, rowptr, cursor, rec);

  // ---- layer 1 (H=4) ----
  gemm1_mfma<<<dim3(235, 4), 256, 0, stream>>>(x, W1t, as1, ad1, xs1b, alsrc, aldst);
  agg_kernel<4><<<7500, 256, 0, stream>>>(rowptr, rec, alsrc, aldst, xs1b, bias1, h1b, nullptr);
  bn_stats_b16_kernel<<<256, 256, 0, stream>>>(h1b, stats + 0, stats + 256);

  // ---- layer 2 (H=1) ----
  gemm2_mfma<<<470, 256, 0, stream>>>(h1b, W2t, stats + 0, stats + 256, g1, b1,
                                      as2, ad2, xs2b, alsrc, aldst);
  agg_kernel<1><<<7500, 256, 0, stream>>>(rowptr, rec, alsrc, aldst, xs2b, bias2, nullptr, h2);
  bn_stats_f32_kernel<<<256, 256, 0, stream>>>(h2, stats + 512, stats + 576);

  // ---- pool ----
  gate_kernel<<<7500, 256, 0, stream>>>(h2, stats + 512, stats + 576, g2, b2, Wg, bg, hn, gateb);
  pool_kernel<<<64, 256, 0, stream>>>(batch, gateb, hn, (float*)d_out);
}

// Round 9
// 373.392 us; speedup vs baseline: 1.0240x; 1.0183x over previous
//
#include <hip/hip_runtime.h>
#include <math.h>

#define NN 30000
#define EE 480000
#define BB 64

typedef __bf16 b16x8 __attribute__((ext_vector_type(8)));
typedef float  f32x4 __attribute__((ext_vector_type(4)));
typedef unsigned short u16x8 __attribute__((ext_vector_type(8)));

// ---------------- helpers ----------------
__device__ __forceinline__ float wsum64(float v){
  #pragma unroll
  for (int m = 32; m >= 1; m >>= 1) v += __shfl_xor(v, m, 64);
  return v;
}
__device__ __forceinline__ float wmax64(float v){
  #pragma unroll
  for (int m = 32; m >= 1; m >>= 1) v = fmaxf(v, __shfl_xor(v, m, 64));
  return v;
}
__device__ __forceinline__ float wsum16(float v){
  #pragma unroll
  for (int m = 1; m < 16; m <<= 1) v += __shfl_xor(v, m, 64);
  return v;
}
__device__ __forceinline__ unsigned short f2b(float f){   // fp32 -> bf16 RNE
  union { float f; unsigned u; } v; v.f = f;
  unsigned r = v.u + 0x7fffu + ((v.u >> 16) & 1u);
  return (unsigned short)(r >> 16);
}
__device__ __forceinline__ float b2f(unsigned short u){
  union { unsigned u; float f; } v; v.u = ((unsigned)u) << 16;
  return v.f;
}

// ---------------- CSR build ----------------
__global__ void hist_kernel(const int* __restrict__ dst, int* __restrict__ deg){
  int e = blockIdx.x*256 + threadIdx.x;
  if (e < EE) atomicAdd(&deg[dst[e]], 1);
}

// one-pass multi-block scan: block b redundantly sums deg[0..b*256) then LDS-scans its 256.
__global__ __launch_bounds__(256) void scan_kernel(const int* __restrict__ deg, int* __restrict__ rowptr){
  __shared__ int s[256];
  __shared__ int wred[4];
  const int b = blockIdx.x, tid = threadIdx.x;
  const int base = b*256;
  int part = 0;
  for (int idx = tid; idx < base; idx += 256) part += deg[idx];
  #pragma unroll
  for (int m = 32; m >= 1; m >>= 1) part += __shfl_xor(part, m, 64);
  if ((tid & 63) == 0) wred[tid >> 6] = part;
  __syncthreads();
  int offset = wred[0] + wred[1] + wred[2] + wred[3];
  int n = base + tid;
  int d = (n < NN) ? deg[n] : 0;
  s[tid] = d;
  __syncthreads();
  for (int off = 1; off < 256; off <<= 1){
    int v = (tid >= off) ? s[tid - off] : 0;
    __syncthreads();
    s[tid] += v;
    __syncthreads();
  }
  if (n < NN) rowptr[n] = offset + s[tid] - d;   // exclusive
  if (b == 0 && tid == 0) rowptr[NN] = EE;
}

// ---------------- prep: fully parallel W transposes (bf16) + wae dots ----------------
__global__ void prep_kernel(const float* __restrict__ W1, const float* __restrict__ W2,
                            const float* __restrict__ We1, const float* __restrict__ ae1,
                            const float* __restrict__ We2, const float* __restrict__ ae2,
                            unsigned short* __restrict__ W1t, unsigned short* __restrict__ W2t,
                            float* __restrict__ wae){
  int t = threadIdx.x, b = blockIdx.x;
  if (b < 128){
    W1t[t*128 + b] = f2b(W1[b*256 + t]);
  } else if (b < 384){
    int k = b - 128;
    if (t < 64) W2t[t*256 + k] = f2b(W2[k*64 + t]);
  } else {
    if (t < 128){
      int h = t >> 5, k = t & 31;
      float s = 0.f;
      for (int f = 0; f < 64; f++) s += We1[k*256 + h*64 + f] * ae1[h*64 + f];
      wae[h*32 + k] = s;
    } else if (t < 160){
      int k = t - 128;
      float s = 0.f;
      for (int f = 0; f < 64; f++) s += We2[k*64 + f] * ae2[f];
      wae[128 + k] = s;
    }
  }
}

// ---------------- fused edge pass: 8 lanes/edge, early atomic, 32B + 8B records ----------------
// rec[slot] (8 floats): [0..3]=edot1, [4]=edot2, [5]=src(int bits), [6,7]=pad
// rec8[slot] (float2): {edot2, src(int bits)}
__global__ __launch_bounds__(256) void edge_kernel(const float* __restrict__ ea,
    const float* __restrict__ wae, const int* __restrict__ src, const int* __restrict__ dst,
    const int* __restrict__ rowptr, int* __restrict__ cursor,
    float* __restrict__ rec, float2* __restrict__ rec8){
  __shared__ float s_w[160];
  if (threadIdx.x < 160) s_w[threadIdx.x] = wae[threadIdx.x];
  __syncthreads();
  const int lane = threadIdx.x & 63;
  const int il = lane & 7;
  const int e = blockIdx.x*32 + (threadIdx.x >> 3);
  if (e >= EE) return;
  // issue the slot chain FIRST so it overlaps the ea load latency
  int slot = 0, sv = 0;
  if (il == 0){
    int dd = dst[e];
    slot = rowptr[dd] + atomicAdd(&cursor[dd], 1);
    sv = src[e];
  }
  float4 v = *(const float4*)(ea + (size_t)e*32 + il*4);   // 1KB per wave, coalesced
  float dots[5];
  #pragma unroll
  for (int h = 0; h < 5; h++){
    float4 w = *(const float4*)&s_w[h*32 + il*4];
    dots[h] = v.x*w.x + v.y*w.y + v.z*w.z + v.w*w.w;
  }
  #pragma unroll
  for (int m = 1; m < 8; m <<= 1)
    #pragma unroll
    for (int h = 0; h < 5; h++) dots[h] += __shfl_xor(dots[h], m, 64);
  slot = __shfl(slot, lane & ~7, 64);
  sv   = __shfl(sv,   lane & ~7, 64);
  if (il == 0){
    float4 lo; lo.x = dots[0]; lo.y = dots[1]; lo.z = dots[2]; lo.w = dots[3];
    *(float4*)(rec + (size_t)slot*8) = lo;
  } else if (il == 1){
    float4 hi; hi.x = dots[4]; hi.y = __int_as_float(sv); hi.z = 0.f; hi.w = 0.f;
    *(float4*)(rec + (size_t)slot*8 + 4) = hi;
  } else if (il == 2){
    float2 r8; r8.x = dots[4]; r8.y = __int_as_float(sv);
    rec8[slot] = r8;
  }
}

// ---------------- GEMM1: MFMA bf16, 128 rows, 2 heads per block (grid 235 x 2) ----------------
__global__ __launch_bounds__(256) void gemm1_mfma(const float* __restrict__ x,
    const unsigned short* __restrict__ Bt, const float* __restrict__ a_s, const float* __restrict__ a_d,
    unsigned short* __restrict__ out, float* __restrict__ alsrc, float* __restrict__ aldst){
  __shared__ unsigned short As[128*136];
  __shared__ unsigned short Bs[64*136];
  const int tid = threadIdx.x;
  const int w = tid >> 6, lane = tid & 63;
  const int c = lane & 15, gq = lane >> 4;
  const int m0 = blockIdx.x * 128;
  const int h0 = blockIdx.y * 2;
  // stage A once (fp32 -> bf16)
  #pragma unroll
  for (int q = 0; q < 16; q++){
    int ch = tid*16 + q;
    int r = ch >> 5, off = (ch & 31)*4;
    int grow = m0 + r;
    ushort4 o;
    if (grow < NN){
      float4 v = *(const float4*)(x + (size_t)grow*128 + off);
      o.x = f2b(v.x); o.y = f2b(v.y); o.z = f2b(v.z); o.w = f2b(v.w);
    } else o = make_ushort4(0,0,0,0);
    *(ushort4*)&As[r*136 + off] = o;
  }
  #pragma unroll
  for (int q = 0; q < 4; q++){
    int ch = tid*4 + q;
    int n = ch >> 4, off = (ch & 15)*8;
    *(ulonglong2*)&Bs[n*136 + off] = *(const ulonglong2*)(Bt + (size_t)(h0*64 + n)*128 + off);
  }
  __syncthreads();
  for (int hi = 0; hi < 2; hi++){
    const int head = h0 + hi;
    f32x4 acc[2][4];
    #pragma unroll
    for (int mt = 0; mt < 2; mt++)
      #pragma unroll
      for (int nt = 0; nt < 4; nt++) acc[mt][nt] = (f32x4){0.f,0.f,0.f,0.f};
    #pragma unroll
    for (int k0 = 0; k0 < 128; k0 += 32){
      b16x8 afr[2], bfr[4];
      #pragma unroll
      for (int mt = 0; mt < 2; mt++)
        afr[mt] = *(const b16x8*)&As[(w*32 + mt*16 + c)*136 + k0 + gq*8];
      #pragma unroll
      for (int nt = 0; nt < 4; nt++)
        bfr[nt] = *(const b16x8*)&Bs[(nt*16 + c)*136 + k0 + gq*8];
      #pragma unroll
      for (int mt = 0; mt < 2; mt++)
        #pragma unroll
        for (int nt = 0; nt < 4; nt++)
          acc[mt][nt] = __builtin_amdgcn_mfma_f32_16x16x32_bf16(afr[mt], bfr[nt], acc[mt][nt], 0, 0, 0);
    }
    __syncthreads();
    if (hi == 0){                          // restage next head's B (overlaps epilogue)
      #pragma unroll
      for (int q = 0; q < 4; q++){
        int ch = tid*4 + q;
        int n = ch >> 4, off = (ch & 15)*8;
        *(ulonglong2*)&Bs[n*136 + off] = *(const ulonglong2*)(Bt + (size_t)((h0+1)*64 + n)*128 + off);
      }
    }
    float asv[4], adv[4];
    #pragma unroll
    for (int nt = 0; nt < 4; nt++){
      asv[nt] = a_s[head*64 + nt*16 + c];
      adv[nt] = a_d[head*64 + nt*16 + c];
    }
    #pragma unroll
    for (int mt = 0; mt < 2; mt++){
      int base_row = m0 + w*32 + mt*16 + gq*4;
      #pragma unroll
      for (int r = 0; r < 4; r++){
        int row = base_row + r;
        float ps = 0.f, pd = 0.f;
        #pragma unroll
        for (int nt = 0; nt < 4; nt++){
          ps += acc[mt][nt][r] * asv[nt];
          pd += acc[mt][nt][r] * adv[nt];
        }
        ps = wsum16(ps); pd = wsum16(pd);
        if (row < NN){
          if (c == 0){
            alsrc[(size_t)row*4 + head] = ps;
            aldst[(size_t)row*4 + head] = pd;
          }
          #pragma unroll
          for (int nt = 0; nt < 4; nt++)
            out[(size_t)row*256 + head*64 + nt*16 + c] = f2b(acc[mt][nt][r]);
        }
      }
    }
    if (hi == 0) __syncthreads();
  }
}

// ---------------- GEMM2: MFMA bf16, 128-row tile, BN(from raw stats)+ReLU fused on A ----------------
__global__ __launch_bounds__(256) void gemm2_mfma(const unsigned short* __restrict__ Ab,
    const unsigned short* __restrict__ Bt,
    const float* __restrict__ cs, const float* __restrict__ csq,
    const float* __restrict__ g, const float* __restrict__ b,
    const float* __restrict__ a_s, const float* __restrict__ a_d,
    unsigned short* __restrict__ out, float* __restrict__ alsrc, float* __restrict__ aldst){
  __shared__ unsigned short As[128*136];
  __shared__ unsigned short Bs[64*136];
  __shared__ float s_scale[256], s_shift[256];
  const int tid = threadIdx.x;
  const int w = tid >> 6, lane = tid & 63;
  const int c = lane & 15, gq = lane >> 4;
  const int m0 = blockIdx.x * 128;
  {
    float mu  = cs[tid]  * (1.f/NN);
    float var = csq[tid] * (1.f/NN) - mu*mu;
    float rs  = rsqrtf(var + 1e-5f);
    float sc  = rs * g[tid];
    s_scale[tid] = sc;
    s_shift[tid] = b[tid] - mu*sc;
  }
  __syncthreads();
  f32x4 acc[2][4];
  #pragma unroll
  for (int mt = 0; mt < 2; mt++)
    #pragma unroll
    for (int nt = 0; nt < 4; nt++) acc[mt][nt] = (f32x4){0.f,0.f,0.f,0.f};
  for (int kp = 0; kp < 256; kp += 128){
    #pragma unroll
    for (int q = 0; q < 16; q++){
      int ch = tid*16 + q;
      int r = ch >> 5, off = (ch & 31)*4;
      int grow = m0 + r;
      ushort4 o;
      if (grow < NN){
        ushort4 v = *(const ushort4*)(Ab + (size_t)grow*256 + kp + off);
        float4 sc = *(const float4*)&s_scale[kp + off];
        float4 sh = *(const float4*)&s_shift[kp + off];
        o.x = f2b(fmaxf(fmaf(b2f(v.x), sc.x, sh.x), 0.f));
        o.y = f2b(fmaxf(fmaf(b2f(v.y), sc.y, sh.y), 0.f));
        o.z = f2b(fmaxf(fmaf(b2f(v.z), sc.z, sh.z), 0.f));
        o.w = f2b(fmaxf(fmaf(b2f(v.w), sc.w, sh.w), 0.f));
      } else o = make_ushort4(0,0,0,0);
      *(ushort4*)&As[r*136 + off] = o;
    }
    #pragma unroll
    for (int q = 0; q < 4; q++){
      int ch = tid*4 + q;
      int n = ch >> 4, off = (ch & 15)*8;
      *(ulonglong2*)&Bs[n*136 + off] = *(const ulonglong2*)(Bt + (size_t)n*256 + kp + off);
    }
    __syncthreads();
    #pragma unroll
    for (int k0 = 0; k0 < 128; k0 += 32){
      b16x8 afr[2], bfr[4];
      #pragma unroll
      for (int mt = 0; mt < 2; mt++)
        afr[mt] = *(const b16x8*)&As[(w*32 + mt*16 + c)*136 + k0 + gq*8];
      #pragma unroll
      for (int nt = 0; nt < 4; nt++)
        bfr[nt] = *(const b16x8*)&Bs[(nt*16 + c)*136 + k0 + gq*8];
      #pragma unroll
      for (int mt = 0; mt < 2; mt++)
        #pragma unroll
        for (int nt = 0; nt < 4; nt++)
          acc[mt][nt] = __builtin_amdgcn_mfma_f32_16x16x32_bf16(afr[mt], bfr[nt], acc[mt][nt], 0, 0, 0);
    }
    __syncthreads();
  }
  float asv[4], adv[4];
  #pragma unroll
  for (int nt = 0; nt < 4; nt++){
    asv[nt] = a_s[nt*16 + c];
    adv[nt] = a_d[nt*16 + c];
  }
  #pragma unroll
  for (int mt = 0; mt < 2; mt++){
    int base_row = m0 + w*32 + mt*16 + gq*4;
    #pragma unroll
    for (int r = 0; r < 4; r++){
      int row = base_row + r;
      float ps = 0.f, pd = 0.f;
      #pragma unroll
      for (int nt = 0; nt < 4; nt++){
        ps += acc[mt][nt][r] * asv[nt];
        pd += acc[mt][nt][r] * adv[nt];
      }
      ps = wsum16(ps); pd = wsum16(pd);
      if (row < NN){
        if (c == 0){
          alsrc[row] = ps;
          aldst[row] = pd;
        }
        #pragma unroll
        for (int nt = 0; nt < 4; nt++)
          out[(size_t)row*64 + nt*16 + c] = f2b(acc[mt][nt][r]);
      }
    }
  }
}

// ---------------- segment softmax + wide bf16 gather (round-6 body) ----------------
// H=4: rec is the 32B-record array. H=1: rec is the compact float2 array {edot2, src}.
template<int H>
__global__ __launch_bounds__(256) void agg_kernel(const int* __restrict__ rowptr,
    const float* __restrict__ rec,
    const float* __restrict__ al_src, const float* __restrict__ al_dst,
    const unsigned short* __restrict__ xsb, const float* __restrict__ bias,
    unsigned short* __restrict__ outb, float* __restrict__ outf){
  constexpr int CH = 128;
  __shared__ float s_e_all[4][CH*H];
  __shared__ int   s_src_all[4][CH];
  const int wid  = threadIdx.x >> 6;
  const int lane = threadIdx.x & 63;
  const int i = blockIdx.x*4 + wid;
  float* s_e  = s_e_all[wid];
  int*   s_src = s_src_all[wid];
  const int r0 = rowptr[i];
  const int d  = rowptr[i+1] - r0;
  float ad[H], asi[H];
  #pragma unroll
  for (int h = 0; h < H; h++){ ad[h] = al_dst[(size_t)i*H+h]; asi[h] = al_src[(size_t)i*H+h]; }
  float sesum[H], m[H];
  #pragma unroll
  for (int h = 0; h < H; h++){ sesum[h] = 0.f; m[h] = -1e30f; }
  for (int t = lane; t < d; t += 64){
    float al[H];
    int sn;
    if constexpr (H == 4){
      const float* rp = rec + (size_t)(r0 + t)*8;
      float4 ev = *(const float4*)rp;
      float2 hi = *(const float2*)(rp + 4);
      sn = __float_as_int(hi.y);
      float4 av = *(const float4*)(al_src + (size_t)sn*4);
      al[0]=av.x+ad[0]+ev.x; al[1]=av.y+ad[1]+ev.y; al[2]=av.z+ad[2]+ev.z; al[3]=av.w+ad[3]+ev.w;
      sesum[0]+=ev.x; sesum[1]+=ev.y; sesum[2]+=ev.z; sesum[3]+=ev.w;
    } else {
      float2 hi = ((const float2*)rec)[r0 + t];
      sn = __float_as_int(hi.y);
      al[0] = al_src[sn] + ad[0] + hi.x;
      sesum[0] += hi.x;
    }
    if (t < CH) s_src[t] = sn;
    #pragma unroll
    for (int h = 0; h < H; h++){
      float a = al[h]; a = a > 0.f ? a : 0.2f*a;
      if (t < CH) s_e[t*H+h] = a;
      m[h] = fmaxf(m[h], a);
    }
  }
  float invd = (d > 0) ? 1.f/(float)d : 0.f;
  float sa[H];
  #pragma unroll
  for (int h = 0; h < H; h++){
    sesum[h] = wsum64(sesum[h]);
    m[h] = wmax64(m[h]);
    float a = asi[h] + ad[h] + sesum[h]*invd;
    sa[h] = a > 0.f ? a : 0.2f*a;
    m[h] = fmaxf(m[h], sa[h]);
  }
  float acc8[8];
  #pragma unroll
  for (int j = 0; j < 8; j++) acc8[j] = 0.f;
  float dpart[H];
  #pragma unroll
  for (int h = 0; h < H; h++) dpart[h] = 0.f;
  const int half = lane >> 5, il5 = lane & 31;   // H==4 mapping
  const int grp  = lane >> 3, il3 = lane & 7;    // H==1 mapping
  int c0 = 0;
  while (c0 < d){
    int cl = min(CH, d - c0);
    if (c0 > 0){
      for (int t = lane; t < cl; t += 64){
        if constexpr (H == 4){
          const float* rp = rec + (size_t)(r0 + c0 + t)*8;
          float4 ev = *(const float4*)rp;
          float2 hi = *(const float2*)(rp + 4);
          int sn = __float_as_int(hi.y);
          s_src[t] = sn;
          float4 av = *(const float4*)(al_src + (size_t)sn*4);
          float a0=av.x+ad[0]+ev.x, a1=av.y+ad[1]+ev.y, a2=av.z+ad[2]+ev.z, a3=av.w+ad[3]+ev.w;
          s_e[t*4+0]=a0>0.f?a0:0.2f*a0; s_e[t*4+1]=a1>0.f?a1:0.2f*a1;
          s_e[t*4+2]=a2>0.f?a2:0.2f*a2; s_e[t*4+3]=a3>0.f?a3:0.2f*a3;
        } else {
          float2 hi = ((const float2*)rec)[r0 + c0 + t];
          int sn = __float_as_int(hi.y);
          s_src[t] = sn;
          float a = al_src[sn] + ad[0] + hi.x;
          s_e[t] = a > 0.f ? a : 0.2f*a;
        }
      }
    }
    for (int t = lane; t < cl; t += 64){
      #pragma unroll
      for (int h = 0; h < H; h++){
        float e = __expf(s_e[t*H+h] - m[h]);
        s_e[t*H+h] = e;
        dpart[h] += e;
      }
    }
    __builtin_amdgcn_wave_barrier();
    if constexpr (H == 4){
      const int hd = il5 >> 3;
      for (int t = half; t < cl; t += 2){
        int sn = s_src[t];
        float wv = s_e[t*4 + hd];
        u16x8 u = *(const u16x8*)(xsb + (size_t)sn*256 + il5*8);
        #pragma unroll
        for (int j = 0; j < 8; j++) acc8[j] += wv * b2f(u[j]);
      }
    } else {
      for (int t = grp; t < cl; t += 8){
        int sn = s_src[t];
        float wv = s_e[t];
        u16x8 u = *(const u16x8*)(xsb + (size_t)sn*64 + il3*8);
        #pragma unroll
        for (int j = 0; j < 8; j++) acc8[j] += wv * b2f(u[j]);
      }
    }
    __builtin_amdgcn_wave_barrier();
    c0 += CH;
  }
  float es[H];
  #pragma unroll
  for (int h = 0; h < H; h++) es[h] = __expf(sa[h] - m[h]);
  if (lane == 0){
    #pragma unroll
    for (int h = 0; h < H; h++) dpart[h] += es[h];
  }
  if constexpr (H == 4){
    if (half == 0){
      float wv = es[il5 >> 3];
      u16x8 u = *(const u16x8*)(xsb + (size_t)i*256 + il5*8);
      #pragma unroll
      for (int j = 0; j < 8; j++) acc8[j] += wv * b2f(u[j]);
    }
  } else {
    if (grp == 0){
      float wv = es[0];
      u16x8 u = *(const u16x8*)(xsb + (size_t)i*64 + il3*8);
      #pragma unroll
      for (int j = 0; j < 8; j++) acc8[j] += wv * b2f(u[j]);
    }
  }
  float denom[H];
  #pragma unroll
  for (int h = 0; h < H; h++) denom[h] = wsum64(dpart[h]);
  if constexpr (H == 4){
    #pragma unroll
    for (int j = 0; j < 8; j++) acc8[j] += __shfl_xor(acc8[j], 32, 64);
    if (lane < 32){
      float inv = 1.f / denom[il5 >> 3];
      u16x8 o;
      #pragma unroll
      for (int j = 0; j < 8; j++) o[j] = f2b(acc8[j]*inv + bias[il5*8 + j]);
      *(u16x8*)(outb + (size_t)i*256 + il5*8) = o;
    }
  } else {
    #pragma unroll
    for (int j = 0; j < 8; j++){
      acc8[j] += __shfl_xor(acc8[j], 8, 64);
      acc8[j] += __shfl_xor(acc8[j], 16, 64);
      acc8[j] += __shfl_xor(acc8[j], 32, 64);
    }
    if (lane < 8){
      float inv = 1.f / denom[0];
      float4 o0, o1;
      o0.x = acc8[0]*inv + bias[il3*8+0]; o0.y = acc8[1]*inv + bias[il3*8+1];
      o0.z = acc8[2]*inv + bias[il3*8+2]; o0.w = acc8[3]*inv + bias[il3*8+3];
      o1.x = acc8[4]*inv + bias[il3*8+4]; o1.y = acc8[5]*inv + bias[il3*8+5];
      o1.z = acc8[6]*inv + bias[il3*8+6]; o1.w = acc8[7]*inv + bias[il3*8+7];
      *(float4*)(outf + (size_t)i*64 + il3*8)     = o0;
      *(float4*)(outf + (size_t)i*64 + il3*8 + 4) = o1;
    }
  }
}

// ---------------- BN stats ----------------
__global__ __launch_bounds__(256) void bn_stats_b16_kernel(const unsigned short* __restrict__ h,
    float* __restrict__ cs, float* __restrict__ csq){
  __shared__ float s_red[4][256], q_red[4][256];
  const int tid = threadIdx.x;
  const int wv = tid >> 6, lane = tid & 63;
  const int rg = lane >> 5, cg = lane & 31;
  float s8[8], q8[8];
  #pragma unroll
  for (int j = 0; j < 8; j++){ s8[j] = 0.f; q8[j] = 0.f; }
  for (int chunk = blockIdx.x; chunk < 3750; chunk += 256){
    int r = chunk*8 + wv*2 + rg;
    u16x8 u = *(const u16x8*)(h + (size_t)r*256 + cg*8);
    #pragma unroll
    for (int j = 0; j < 8; j++){
      float v = b2f(u[j]);
      s8[j] += v; q8[j] += v*v;
    }
  }
  #pragma unroll
  for (int j = 0; j < 8; j++){
    s8[j] += __shfl_xor(s8[j], 32, 64);
    q8[j] += __shfl_xor(q8[j], 32, 64);
  }
  if (lane < 32){
    #pragma unroll
    for (int j = 0; j < 8; j++){
      s_red[wv][cg*8 + j] = s8[j];
      q_red[wv][cg*8 + j] = q8[j];
    }
  }
  __syncthreads();
  if (tid < 256){
    float ts = s_red[0][tid] + s_red[1][tid] + s_red[2][tid] + s_red[3][tid];
    float tq = q_red[0][tid] + q_red[1][tid] + q_red[2][tid] + q_red[3][tid];
    atomicAdd(&cs[tid], ts);
    atomicAdd(&csq[tid], tq);
  }
}

__global__ __launch_bounds__(256) void bn_stats_f32_kernel(const float* __restrict__ h,
    float* __restrict__ cs, float* __restrict__ csq){
  int col = threadIdx.x & 63;
  int ro  = threadIdx.x >> 6;
  float s = 0.f, s2 = 0.f;
  for (int r = blockIdx.x*4 + ro; r < NN; r += 1024){
    float v = h[(size_t)r*64 + col];
    s += v; s2 += v*v;
  }
  atomicAdd(&cs[col], s);
  atomicAdd(&csq[col], s2);
}

// ---------------- pooling ----------------
__global__ __launch_bounds__(256) void gate_kernel(const float* __restrict__ h,
    const float* __restrict__ cs, const float* __restrict__ csq,
    const float* __restrict__ g2, const float* __restrict__ b2,
    const float* __restrict__ Wg, const float* __restrict__ bg,
    float* __restrict__ gate){
  int wid = threadIdx.x >> 6, lane = threadIdx.x & 63;
  int n = blockIdx.x*4 + wid;
  float mu  = cs[lane]  * (1.f/NN);
  float var = csq[lane] * (1.f/NN) - mu*mu;
  float rs  = rsqrtf(var + 1e-5f);
  float sc  = rs * g2[lane];
  float sh  = b2[lane] - mu*sc;
  float v = h[(size_t)n*64 + lane];
  float xx = fmaxf(fmaf(v, sc, sh), 0.f);
  float p = wsum64(xx * Wg[lane]);
  if (lane == 0) gate[n] = p + bg[0];
}

__global__ __launch_bounds__(256) void pool_kernel(const int* __restrict__ batch,
    const float* __restrict__ gate, const float* __restrict__ h2,
    const float* __restrict__ cs, const float* __restrict__ csq,
    const float* __restrict__ g2, const float* __restrict__ b2,
    float* __restrict__ out){
  __shared__ float red[256];
  __shared__ float a_red[4][64], w_red[4];
  __shared__ int seb[2];
  int b = blockIdx.x, tid = threadIdx.x;
  int wv = tid >> 6, lane = tid & 63;
  if (tid < 2){
    int target = b + tid;
    int lo = 0, hi = NN;
    while (lo < hi){ int mid = (lo+hi) >> 1; if (batch[mid] < target) lo = mid+1; else hi = mid; }
    seb[tid] = lo;
  }
  __syncthreads();
  int s = seb[0], e = seb[1];
  if (e <= s){ if (tid < 64) out[b*64 + tid] = 0.f; return; }
  float mloc = -1e30f;
  for (int n = s + tid; n < e; n += 256) mloc = fmaxf(mloc, gate[n]);
  mloc = wmax64(mloc);
  if (lane == 0) red[wv] = mloc;
  __syncthreads();
  float m = fmaxf(fmaxf(red[0], red[1]), fmaxf(red[2], red[3]));
  int rgrp = tid >> 4, cq = tid & 15;
  // per-lane BN2 scale/shift for its 4 cols
  float4 csv = *(const float4*)(cs + cq*4);
  float4 cqv = *(const float4*)(csq + cq*4);
  float4 gv  = *(const float4*)(g2 + cq*4);
  float4 bv  = *(const float4*)(b2 + cq*4);
  float4 scv, shv;
  {
    float mu0 = csv.x*(1.f/NN), mu1 = csv.y*(1.f/NN), mu2 = csv.z*(1.f/NN), mu3 = csv.w*(1.f/NN);
    scv.x = rsqrtf(cqv.x*(1.f/NN) - mu0*mu0 + 1e-5f) * gv.x;
    scv.y = rsqrtf(cqv.y*(1.f/NN) - mu1*mu1 + 1e-5f) * gv.y;
    scv.z = rsqrtf(cqv.z*(1.f/NN) - mu2*mu2 + 1e-5f) * gv.z;
    scv.w = rsqrtf(cqv.w*(1.f/NN) - mu3*mu3 + 1e-5f) * gv.w;
    shv.x = bv.x - mu0*scv.x; shv.y = bv.y - mu1*scv.y;
    shv.z = bv.z - mu2*scv.z; shv.w = bv.w - mu3*scv.w;
  }
  f32x4 acc = (f32x4){0.f,0.f,0.f,0.f};
  float wp = 0.f;
  for (int n = s + rgrp; n < e; n += 16){
    float wgt = __expf(gate[n] - m);
    float4 v = *(const float4*)(h2 + (size_t)n*64 + cq*4);
    acc[0] += wgt*fmaxf(fmaf(v.x, scv.x, shv.x), 0.f);
    acc[1] += wgt*fmaxf(fmaf(v.y, scv.y, shv.y), 0.f);
    acc[2] += wgt*fmaxf(fmaf(v.z, scv.z, shv.z), 0.f);
    acc[3] += wgt*fmaxf(fmaf(v.w, scv.w, shv.w), 0.f);
    if (cq == 0) wp += wgt;
  }
  #pragma unroll
  for (int j = 0; j < 4; j++){
    acc[j] += __shfl_xor(acc[j], 16, 64);
    acc[j] += __shfl_xor(acc[j], 32, 64);
  }
  wp += __shfl_xor(wp, 16, 64);
  wp += __shfl_xor(wp, 32, 64);
  if (lane < 16){
    #pragma unroll
    for (int j = 0; j < 4; j++) a_red[wv][lane*4 + j] = acc[j];
  }
  if (lane == 0) w_red[wv] = wp;
  __syncthreads();
  if (tid < 64){
    float tot = a_red[0][tid] + a_red[1][tid] + a_red[2][tid] + a_red[3][tid];
    float wsm = w_red[0] + w_red[1] + w_red[2] + w_red[3];
    out[b*64 + tid] = tot / wsm;
  }
}

// ---------------- host ----------------
extern "C" void kernel_launch(void* const* d_in, const int* in_sizes, int n_in,
                              void* d_out, int out_size, void* d_ws, size_t ws_size,
                              hipStream_t stream){
  const float* x     = (const float*)d_in[0];
  const float* ea    = (const float*)d_in[1];
  const int*   ei    = (const int*)d_in[2];
  const int*   batch = (const int*)d_in[3];
  const float* W1    = (const float*)d_in[4];
  const float* We1   = (const float*)d_in[5];
  const float* as1   = (const float*)d_in[6];
  const float* ad1   = (const float*)d_in[7];
  const float* ae1   = (const float*)d_in[8];
  const float* bias1 = (const float*)d_in[9];
  const float* g1    = (const float*)d_in[10];
  const float* b1    = (const float*)d_in[11];
  const float* W2    = (const float*)d_in[12];
  const float* We2   = (const float*)d_in[13];
  const float* as2   = (const float*)d_in[14];
  const float* ad2   = (const float*)d_in[15];
  const float* ae2   = (const float*)d_in[16];
  const float* bias2 = (const float*)d_in[17];
  const float* g2    = (const float*)d_in[18];
  const float* b2    = (const float*)d_in[19];
  const float* Wg    = (const float*)d_in[20];
  const float* bg    = (const float*)d_in[21];
  const int* srcI = ei;
  const int* dstI = ei + EE;

  char* ws = (char*)d_ws;
  int*   deg    = (int*)(ws + 0);
  int*   cursor = (int*)(ws + 120064);
  float* stats  = (float*)(ws + 240128);   // cs1@0 csq1@256 cs2@512 csq2@576
  int*   rowptr = (int*)(ws + 244224);
  float* wae    = (float*)(ws + 364288);
  unsigned short* W1t = (unsigned short*)(ws + 365056);
  unsigned short* W2t = (unsigned short*)(ws + 430592);
  float* alsrc  = (float*)(ws + 463360);
  float* aldst  = (float*)(ws + 943360);
  float* gateb  = (float*)(ws + 1423360);
  float* rec    = (float*)(ws + 1543424);   // E * 32B records
  unsigned short* xs1b = (unsigned short*)(ws + 16903424); // 30000*256 bf16
  unsigned short* h1b  = (unsigned short*)(ws + 32263424); // 30000*256 bf16
  unsigned short* xs2b = (unsigned short*)(ws + 47623424); // 30000*64 bf16
  float* h2     = (float*)(ws + 51463424);  // 30000*64 f32
  float2* rec8  = (float2*)(ws + 59143424); // E * 8B records
  // total ~63 MB

  (void)hipMemsetAsync(ws, 0, 244224, stream);   // deg, cursor, stats

  hist_kernel<<<1875, 256, 0, stream>>>(dstI, deg);
  scan_kernel<<<118, 256, 0, stream>>>(deg, rowptr);
  prep_kernel<<<385, 256, 0, stream>>>(W1, W2, We1, ae1, We2, ae2, W1t, W2t, wae);
  edge_kernel<<<15000, 256, 0, stream>>>(ea, wae, srcI, dstI, rowptr, cursor, rec, rec8);

  // ---- layer 1 (H=4) ----
  gemm1_mfma<<<dim3(235, 2), 256, 0, stream>>>(x, W1t, as1, ad1, xs1b, alsrc, aldst);
  agg_kernel<4><<<7500, 256, 0, stream>>>(rowptr, rec, alsrc, aldst, xs1b, bias1, h1b, nullptr);
  bn_stats_b16_kernel<<<256, 256, 0, stream>>>(h1b, stats + 0, stats + 256);

  // ---- layer 2 (H=1) ----
  gemm2_mfma<<<235, 256, 0, stream>>>(h1b, W2t, stats + 0, stats + 256, g1, b1,
                                      as2, ad2, xs2b, alsrc, aldst);
  agg_kernel<1><<<7500, 256, 0, stream>>>(rowptr, (const float*)rec8, alsrc, aldst, xs2b, bias2, nullptr, h2);
  bn_stats_f32_kernel<<<256, 256, 0, stream>>>(h2, stats + 512, stats + 576);

  // ---- pool (BN2 applied inline in gate and pool) ----
  gate_kernel<<<7500, 256, 0, stream>>>(h2, stats + 512, stats + 576, g2, b2, Wg, bg, gateb);
  pool_kernel<<<64, 256, 0, stream>>>(batch, gateb, h2, stats + 512, stats + 576, g2, b2, (float*)d_out);
}